// Round 13
// baseline (322.697 us; speedup 1.0000x reference)
//
#include <hip/hip_runtime.h>

// SelfAttention: B=4, S=2048, D=1024, fp32 in/out.
// q=x@Wq^T+bq, k=..., v=...; out = softmax(q k^T) @ v   (no 1/sqrt(d) scale)
//
// R11: scores = x G x^T + u 1^T + 1 w^T (G = Wq^T Wk precomputed; one
//   projection GEMM t = x G instead of two; biases exact f32 epilogue adds).
// Carried: R8 fragment-linear LDS (bank conflicts 0), R9 counted-vmcnt +
//   raw s_barrier (T4), R10 XCD swizzle, R13/R15 f16 GEMMs (absmax 0.1016
//   accepted), R17/R18 256x128 tile / wave-tile 128x64 (the per-MFMA
//   LDS/barrier ratio lever — validated 3 rounds running).
// R19 (retry): BK 32->64 halves iteration count and barrier pairs per unit
//   work (score was ~58% per-iter barrier/waitcnt overhead). R12's submission
//   died in-harness ("container failed twice"); the only UNTESTED element was
//   the 144KB static LDS (3 buffers). At BK=64 the ~1300cyc compute phase
//   already covers the ~900cyc HBM miss, so the 3rd buffer is not load-
//   bearing: this retry uses 2 x 48KB = 96KB LDS (below the 128KB
//   guide-proven ceiling), depth-1 prefetch, 12 gl_lds/stage, vmcnt
//   keep-12 / drain-0. Occupancy 1 block/CU either way (R18 proved this
//   tile runs fine there). Falsifier unchanged: regression => revert BK=32.

#define Bb 4
#define Ss 2048
#define Dd 1024
#define Mtot 8192  // B*S

typedef _Float16 f16x8 __attribute__((ext_vector_type(8)));
typedef float f32x4 __attribute__((ext_vector_type(4)));
typedef int i32x4 __attribute__((ext_vector_type(4)));
typedef signed char i8x16 __attribute__((ext_vector_type(16)));
typedef unsigned short u16;
typedef unsigned int u32;
typedef unsigned char u8;
typedef u16 u16x8 __attribute__((ext_vector_type(8)));
typedef u16 u16x4 __attribute__((ext_vector_type(4)));
typedef void __attribute__((address_space(1))) gvoid_t;
typedef void __attribute__((address_space(3))) svoid_t;

// ---- W digit scales (powers of two) ----
#define WC 1.953125e-3f               // 2^-9
#define WCI 512.f
#define WFI 131072.f
#define W1S 7.62939453125e-6f         // 2^-17
// G = Wq^T Wk accumulator scales
#define SG00 3.814697265625e-6f       // 2^-18
#define SG01 1.4901161193847656e-8f   // 2^-26
#define SG11 5.820766091346741e-11f   // 2^-34

__device__ __forceinline__ void gl_lds16(const void* g, void* l) {
  __builtin_amdgcn_global_load_lds((gvoid_t*)g, (svoid_t*)l, 16, 0, 0);
}

__device__ __forceinline__ u16 f2h(float f) {
  return __builtin_bit_cast(u16, (_Float16)f);
}
__device__ __forceinline__ f16x8 frag_ld_h(const char* p) {
  u16x8 v = *(const u16x8*)p;
  return __builtin_bit_cast(f16x8, v);
}
__device__ __forceinline__ f32x4 mfma_f16(f16x8 a, f16x8 b, f32x4 c) {
  return __builtin_amdgcn_mfma_f32_16x16x32_f16(a, b, c, 0, 0, 0);
}
__device__ __forceinline__ i32x4 mfma_i8(i32x4 a, i32x4 b, i32x4 c) {
  return __builtin_amdgcn_mfma_i32_16x16x64_i8(a, b, c, 0, 0, 0);
}
// split v into two clamped i8 digits: v ~= d0*cs + d1*(1/fi)
__device__ __forceinline__ void dig2(float v, float cs, float ci, float fi,
                                     int& d0, int& d1) {
  float t = fminf(fmaxf(v * ci, -127.f), 127.f);
  d0 = __float2int_rn(t);
  float res = v - (float)d0 * cs;
  float u = fminf(fmaxf(res * fi, -127.f), 127.f);
  d1 = __float2int_rn(u);
}

// T1: bijective XCD-aware block swizzle (pow2 grids, N%8==0).
template <int GX, int GY, int GZ>
__device__ __forceinline__ void xcd_swz(int& bx, int& by, int& bz) {
  constexpr int N = GX * GY * GZ;
  int flat = (int)blockIdx.x + GX * ((int)blockIdx.y + GY * (int)blockIdx.z);
  int s = (flat & 7) * (N >> 3) + (flat >> 3);
  bx = s & (GX - 1);
  by = (s / GX) & (GY - 1);
  bz = s / (GX * GY);
}

// T4 pipeline sync: wait with N loads still in flight, then raw barrier.
__device__ __forceinline__ void wait_bar_keep12() {
  asm volatile("s_waitcnt vmcnt(12)" ::: "memory");
  __builtin_amdgcn_s_barrier();
  __builtin_amdgcn_sched_barrier(0);
}
__device__ __forceinline__ void wait_bar_keep8() {
  asm volatile("s_waitcnt vmcnt(8)" ::: "memory");
  __builtin_amdgcn_s_barrier();
  __builtin_amdgcn_sched_barrier(0);
}
__device__ __forceinline__ void wait_bar_drain() {
  asm volatile("s_waitcnt vmcnt(0)" ::: "memory");
  __builtin_amdgcn_s_barrier();
  __builtin_amdgcn_sched_barrier(0);
}
__device__ __forceinline__ void end_bar() {
  __builtin_amdgcn_sched_barrier(0);
  __builtin_amdgcn_s_barrier();
}

// Fragment-linear stager (R8): LDS dest lane-linear, GLOBAL source permuted so
// each 16-row subtile lands as [chunk-group h][chunk lk][row lr]; MFMA fragment
// read is subtile_base + h*1024 + lane*16 -> conflict-free.
template <int ROUNDS, int C>
__device__ __forceinline__ void stageF(const char* g, long row0, long ldb,
                                       long k0b, char* l, int tid) {
#pragma unroll
  for (int r = 0; r < ROUNDS; ++r) {
    int s = r * 256 + tid;
    int sub = s / (16 * C);
    int t = s % (16 * C);
    int h = t >> 6;
    int lk = (t >> 4) & 3;
    int lr = t & 15;
    gl_lds16(g + (row0 + sub * 16 + lr) * ldb + k0b + (h * 4 + lk) * 16,
             l + s * 16);
  }
}

// R19: shared f16 GEMM core, 256x128 tile, 4 waves (2M x 2N), wave-tile
// 128x64 (acc 8x4), BK=64, 2-buffer depth-1 counted-vmcnt pipeline.
// LDS per buffer (48KB): A 256x64 f16 (32KB, subtile stride 2048B) |
// B 128x64 f16 (16KB). Fragment read: subtile*2048 + ks*1024 + lane*16.
template <int NT>
__device__ __forceinline__ void gemm256_core(
    const char* A, const char* B, long m0, long n0, long lda, long ldb,
    char* lds, int tid, int wm, int wn, int lane, f32x4 (&acc)[8][4]) {
  auto stage = [&](char* L, int t) {  // 12 gl_lds per thread
    stageF<8, 8>(A, m0, lda, (long)t * 128, L, tid);          // 256x64
    stageF<4, 8>(B, n0, ldb, (long)t * 128, L + 32768, tid);  // 128x64
  };
  auto compute = [&](const char* L) {
#pragma unroll
    for (int ks = 0; ks < 2; ++ks) {
      f16x8 af[8], bfr[4];
#pragma unroll
      for (int i = 0; i < 8; ++i)
        af[i] = frag_ld_h(L + (wm * 8 + i) * 2048 + ks * 1024 + lane * 16);
#pragma unroll
      for (int i = 0; i < 4; ++i)
        bfr[i] = frag_ld_h(L + 32768 + (wn * 4 + i) * 2048 + ks * 1024 + lane * 16);
      __builtin_amdgcn_s_setprio(1);
#pragma unroll
      for (int mt = 0; mt < 8; ++mt)
#pragma unroll
        for (int nt = 0; nt < 4; ++nt)
          acc[mt][nt] = mfma_f16(af[mt], bfr[nt], acc[mt][nt]);
      __builtin_amdgcn_s_setprio(0);
    }
  };

  char* L0 = lds;
  char* L1 = lds + 49152;
  stage(L0, 0);
  for (int t = 0; t < NT - 1; ++t) {
    char* Lc = (t & 1) ? L1 : L0;
    char* Ln = (t & 1) ? L0 : L1;
    stage(Ln, t + 1);    // lands under compute(t) (~1300 cyc cover)
    wait_bar_keep12();   // 24 outstanding -> 12 == stage(t) landed
    compute(Lc);
    end_bar();           // reads of Lc done; safe to overwrite next iter
  }
  wait_bar_drain();      // stage(NT-1) landed
  compute(((NT - 1) & 1) ? L1 : L0);
}

// ---------------------------------------------------------------- convert W
__global__ void __launch_bounds__(256) convert_w(
    const float* __restrict__ Wq, const float* __restrict__ Wk,
    const float* __restrict__ Wv,
    u8* __restrict__ wq0, u8* __restrict__ wq1,
    u8* __restrict__ wk0, u8* __restrict__ wk1, u16* __restrict__ wvh) {
  long b = blockIdx.x;
  if (b < 2048) {
    int which = (int)(b >> 10);  // 0=q, 1=k
    const float* src = which ? Wk : Wq;
    u8* o0 = which ? wk0 : wq0;
    u8* o1 = which ? wk1 : wq1;
    long i = (b & 1023) * 256 + threadIdx.x;
    f32x4 v = ((const f32x4*)src)[i];
    u32 p0 = 0, p1 = 0;
#pragma unroll
    for (int j = 0; j < 4; ++j) {
      int d0, d1;
      dig2(v[j], WC, WCI, WFI, d0, d1);
      p0 |= ((u32)(d0 & 255)) << (8 * j);
      p1 |= ((u32)(d1 & 255)) << (8 * j);
    }
    ((u32*)o0)[i] = p0;
    ((u32*)o1)[i] = p1;
  } else {
    long i = (b - 2048) * 256 + threadIdx.x;
    f32x4 v = ((const f32x4*)Wv)[i];
    u16x4 h;
#pragma unroll
    for (int j = 0; j < 4; ++j) h[j] = f2h(v[j]);
    ((u16x4*)wvh)[i] = h;
  }
}

// ---------------------------------------------------------------- transpose W digits
__global__ void __launch_bounds__(256) transpose_w(
    const u8* __restrict__ wq0, const u8* __restrict__ wq1,
    const u8* __restrict__ wk0, const u8* __restrict__ wk1,
    u8* __restrict__ wqT0, u8* __restrict__ wqT1,
    u8* __restrict__ wkT0, u8* __restrict__ wkT1) {
  __shared__ u8 T[64][68];
  int a = blockIdx.z;
  const u8* src = a == 0 ? wq0 : a == 1 ? wq1 : a == 2 ? wk0 : wk1;
  u8* dst = a == 0 ? wqT0 : a == 1 ? wqT1 : a == 2 ? wkT0 : wkT1;
  int bi = blockIdx.y, bj = blockIdx.x;
  int t = threadIdx.x, r = t >> 2, c4 = t & 3;
  const u32* s = (const u32*)(src + (long)(bi * 64 + r) * 1024 + bj * 64 + c4 * 16);
  u32 v0 = s[0], v1 = s[1], v2 = s[2], v3 = s[3];
  u32* trow = (u32*)&T[r][c4 * 16];
  trow[0] = v0; trow[1] = v1; trow[2] = v2; trow[3] = v3;
  __syncthreads();
  u32 o[4] = {0, 0, 0, 0};
#pragma unroll
  for (int j = 0; j < 16; ++j)
    o[j >> 2] |= ((u32)T[c4 * 16 + j][r]) << (8 * (j & 3));
  u32* d = (u32*)(dst + (long)(bj * 64 + r) * 1024 + bi * 64 + c4 * 16);
  d[0] = o[0]; d[1] = o[1]; d[2] = o[2]; d[3] = o[3];
}

// ---------------------------------------------------------------- gvec
__global__ void __launch_bounds__(256) gvec_kernel(
    const u8* __restrict__ wqT0, const u8* __restrict__ wqT1,
    const u8* __restrict__ wkT0, const u8* __restrict__ wkT1,
    const float* __restrict__ bq, const float* __restrict__ bk,
    float* __restrict__ gq, float* __restrict__ gk, float* __restrict__ cbuf) {
  __shared__ float sbq[1024], sbk[1024];
  int tid = threadIdx.x;
  ((f32x4*)sbq)[tid] = ((const f32x4*)bq)[tid];
  ((f32x4*)sbk)[tid] = ((const f32x4*)bk)[tid];
  __syncthreads();
  int wave = tid >> 6, lane = tid & 63;
#pragma unroll
  for (int rr = 0; rr < 2; ++rr) {
    int d = blockIdx.x * 8 + wave * 2 + rr;
    i8x16 a0 = *(const i8x16*)(wqT0 + (long)d * 1024 + lane * 16);
    i8x16 a1 = *(const i8x16*)(wqT1 + (long)d * 1024 + lane * 16);
    i8x16 c0 = *(const i8x16*)(wkT0 + (long)d * 1024 + lane * 16);
    i8x16 c1 = *(const i8x16*)(wkT1 + (long)d * 1024 + lane * 16);
    float sq = 0.f, sk = 0.f;
#pragma unroll
    for (int j = 0; j < 16; ++j) {
      sq += ((float)a0[j] * WC + (float)a1[j] * W1S) * sbk[lane * 16 + j];
      sk += ((float)c0[j] * WC + (float)c1[j] * W1S) * sbq[lane * 16 + j];
    }
#pragma unroll
    for (int off = 32; off >= 1; off >>= 1) {
      sq += __shfl_xor(sq, off);
      sk += __shfl_xor(sk, off);
    }
    if (!lane) { gq[d] = sq; gk[d] = sk; }
  }
  if (blockIdx.x == 0 && wave == 0) {
    float c = 0.f;
#pragma unroll
    for (int j = 0; j < 16; ++j) c += sbq[lane * 16 + j] * sbk[lane * 16 + j];
#pragma unroll
    for (int off = 32; off >= 1; off >>= 1) c += __shfl_xor(c, off);
    if (!lane) cbuf[0] = c;
  }
}

// ---------------------------------------------------------------- convert x
// f16 (for t/v/score GEMMs) + row dots u, w.
__global__ void __launch_bounds__(256) convert_x(
    const float* __restrict__ x, const float* __restrict__ gq,
    const float* __restrict__ gk, const float* __restrict__ cbuf,
    u16* __restrict__ xh, float* __restrict__ ubuf, float* __restrict__ wbuf) {
  long b = blockIdx.x;
  int tid = threadIdx.x;
  long i = b * 256 + tid;
  f32x4 v = ((const f32x4*)x)[i];
  u16x4 h;
#pragma unroll
  for (int j = 0; j < 4; ++j) h[j] = f2h(v[j]);
  ((u16x4*)xh)[i] = h;

  f32x4 g4 = ((const f32x4*)gq)[tid];
  f32x4 k4 = ((const f32x4*)gk)[tid];
  float pu = v[0] * g4[0] + v[1] * g4[1] + v[2] * g4[2] + v[3] * g4[3];
  float pw = v[0] * k4[0] + v[1] * k4[1] + v[2] * k4[2] + v[3] * k4[3];
#pragma unroll
  for (int off = 32; off >= 1; off >>= 1) {
    pu += __shfl_xor(pu, off);
    pw += __shfl_xor(pw, off);
  }
  __shared__ float ru[4], rw[4];
  int wave = tid >> 6, lane = tid & 63;
  if (!lane) { ru[wave] = pu; rw[wave] = pw; }
  __syncthreads();
  if (!tid) {
    ubuf[b] = ru[0] + ru[1] + ru[2] + ru[3] + cbuf[0];
    wbuf[b] = rw[0] + rw[1] + rw[2] + rw[3];
  }
}

// ---------------------------------------------------------------- G partial GEMM
__global__ void __launch_bounds__(256, 2) g_part(
    const u8* __restrict__ wqT0, const u8* __restrict__ wqT1,
    const u8* __restrict__ wkT0, const u8* __restrict__ wkT1,
    float* __restrict__ Gpart) {
  __shared__ char lds[65536];
  const int tid = threadIdx.x;
  const int bx = blockIdx.x, by = blockIdx.y, bz = blockIdx.z;
  const long m0 = (long)by * 128;
  const int n0 = bx * 128;
  const int k00 = bz * 256;
  const int wave = tid >> 6, lane = tid & 63;
  const int wm = wave >> 1, wn = wave & 1;
  const int lr = lane & 15, lk = lane >> 4;

  i32x4 accM[4][4] = {};
  i32x4 accX[4][4] = {};
  i32x4 accY[4][4] = {};

  auto stage = [&](char* L, int kk) {
    stageF<2, 4>((const char*)wqT0, m0, 1024, kk, L + 0, tid);
    stageF<2, 4>((const char*)wqT1, m0, 1024, kk, L + 8192, tid);
    stageF<2, 4>((const char*)wkT0, n0, 1024, kk, L + 16384, tid);
    stageF<2, 4>((const char*)wkT1, n0, 1024, kk, L + 24576, tid);
  };
  auto compute = [&](const char* L) {
    i32x4 b0[4], b1[4];
#pragma unroll
    for (int nt = 0; nt < 4; ++nt) {
      int rb = (wn * 4 + nt) * 1024 + lane * 16;
      b0[nt] = *(const i32x4*)(L + 16384 + rb);
      b1[nt] = *(const i32x4*)(L + 24576 + rb);
    }
    __builtin_amdgcn_s_setprio(1);
#pragma unroll
    for (int mt = 0; mt < 4; ++mt) {
      int ra = (wm * 4 + mt) * 1024 + lane * 16;
      i32x4 a0 = *(const i32x4*)(L + ra);
      i32x4 a1 = *(const i32x4*)(L + 8192 + ra);
#pragma unroll
      for (int nt = 0; nt < 4; ++nt) {
        accM[mt][nt] = mfma_i8(a0, b0[nt], accM[mt][nt]);
        accX[mt][nt] = mfma_i8(a0, b1[nt], accX[mt][nt]);
        accX[mt][nt] = mfma_i8(a1, b0[nt], accX[mt][nt]);
        accY[mt][nt] = mfma_i8(a1, b1[nt], accY[mt][nt]);
      }
    }
    __builtin_amdgcn_s_setprio(0);
  };

  stage(lds, k00);
  for (int t = 0; t < 3; ++t) {
    char* L = lds + (t & 1) * 32768;
    stage(lds + ((t + 1) & 1) * 32768, k00 + (t + 1) * 64);
    wait_bar_keep8();
    compute(L);
    end_bar();
  }
  {
    char* L = lds + 32768;
    wait_bar_drain();
    compute(L);
  }

#pragma unroll
  for (int mt = 0; mt < 4; ++mt)
#pragma unroll
    for (int nt = 0; nt < 4; ++nt) {
      int e = n0 + wn * 64 + nt * 16 + lr;
      int gmb = (int)m0 + wm * 64 + mt * 16 + lk * 4;
      f32x4 o;
#pragma unroll
      for (int r = 0; r < 4; ++r)
        o[r] = (float)accM[mt][nt][r] * SG00 + (float)accX[mt][nt][r] * SG01 +
               (float)accY[mt][nt][r] * SG11;
      *(f32x4*)(Gpart + ((long)bz << 20) + (long)e * 1024 + gmb) = o;
    }
}

// ---------------------------------------------------------------- G reduce -> f16
__global__ void __launch_bounds__(256) g_reduce(const float* __restrict__ Gpart,
                                                u16* __restrict__ Gh) {
  int n = blockIdx.x, tid = threadIdx.x;
  long o = (long)n * 1024 + tid * 4;
  f32x4 v = *(const f32x4*)(Gpart + o);
  f32x4 v1 = *(const f32x4*)(Gpart + (1L << 20) + o);
  f32x4 v2 = *(const f32x4*)(Gpart + (2L << 20) + o);
  f32x4 v3 = *(const f32x4*)(Gpart + (3L << 20) + o);
  u16x4 h;
#pragma unroll
  for (int j = 0; j < 4; ++j) h[j] = f2h(v[j] + v1[j] + v2[j] + v3[j]);
  ((u16x4*)Gh)[n * 256 + tid] = h;
}

// ---------------------------------------------------------------- t GEMM (f16, t = x G)
// R19: 256x128 tile, BK=64, 2-buffer (96KB LDS), 1 block/CU.
__global__ void __launch_bounds__(256, 1) t_gemm(
    const u16* __restrict__ xh, const u16* __restrict__ Gh,
    u16* __restrict__ th) {
  __shared__ char lds[98304];
  const int tid = threadIdx.x;
  int bx, by, bz;
  xcd_swz<8, 32, 1>(bx, by, bz);
  const long m0 = (long)by * 256;
  const int n0 = bx * 128;
  const int wave = tid >> 6, lane = tid & 63;
  const int wm = wave >> 1, wn = wave & 1;
  const int lr = lane & 15, lk = lane >> 4;

  f32x4 acc[8][4] = {};
  gemm256_core<16>((const char*)xh, (const char*)Gh, m0, n0,
                   (long)Dd * 2, (long)Dd * 2, lds, tid, wm, wn, lane, acc);

#pragma unroll
  for (int mt = 0; mt < 8; ++mt)
#pragma unroll
    for (int nt = 0; nt < 4; ++nt)
#pragma unroll
      for (int r = 0; r < 4; ++r) {
        long gm = m0 + wm * 128 + mt * 16 + lk * 4 + r;
        int e = n0 + wn * 64 + nt * 16 + lr;
        th[gm * Dd + e] = f2h(acc[mt][nt][r]);
      }
}

// ---------------------------------------------------------------- v GEMM (f16)
// R19: 256x128 tile, BK=64, 2-buffer.
__global__ void __launch_bounds__(256, 1) v_gemm(
    const u16* __restrict__ xh, const u16* __restrict__ wvh,
    const float* __restrict__ bv, u16* __restrict__ vt) {
  __shared__ char lds[98304];
  const int tid = threadIdx.x;
  int bx, by, bz;
  xcd_swz<8, 32, 1>(bx, by, bz);
  const long m0 = (long)by * 256;
  const int n0 = bx * 128;
  const int wave = tid >> 6, lane = tid & 63;
  const int wm = wave >> 1, wn = wave & 1;
  const int lr = lane & 15, lk = lane >> 4;

  f32x4 acc[8][4] = {};
  gemm256_core<16>((const char*)xh, (const char*)wvh, m0, n0,
                   (long)Dd * 2, (long)Dd * 2, lds, tid, wm, wn, lane, acc);

#pragma unroll
  for (int mt = 0; mt < 8; ++mt)
#pragma unroll
    for (int nt = 0; nt < 4; ++nt)
#pragma unroll
      for (int r = 0; r < 4; ++r) {
        long gm = m0 + wm * 128 + mt * 16 + lk * 4 + r;
        int e = n0 + wn * 64 + nt * 16 + lr;
        float v = acc[mt][nt][r] + bv[e];
        long b = gm >> 11, s = gm & 2047;
        vt[(b * Dd + e) * (long)Ss + s] = f2h(v);
      }
}

// ---------------------------------------------------------------- scores GEMM (f16)
// R19: 256x128 tile, BK=64 (NT=16), 2-buffer.
__global__ void __launch_bounds__(256, 1) score_gemm(
    const u16* __restrict__ th, const u16* __restrict__ xh,
    const float* __restrict__ ubuf, const float* __restrict__ wbuf,
    float* __restrict__ scores) {
  __shared__ char lds[98304];
  const int tid = threadIdx.x;
  int bx, by, bz;
  xcd_swz<16, 8, 4>(bx, by, bz);
  const int z = bz;  // batch
  const long base = (long)z * Ss * Dd * 2;  // byte offset
  const long m0 = (long)by * 256;
  const int n0 = bx * 128;
  const int wave = tid >> 6, lane = tid & 63;
  const int wm = wave >> 1, wn = wave & 1;
  const int lr = lane & 15, lk = lane >> 4;

  f32x4 acc[8][4] = {};
  gemm256_core<16>((const char*)th + base, (const char*)xh + base, m0, n0,
                   (long)Dd * 2, (long)Dd * 2, lds, tid, wm, wn, lane, acc);

  float* srow = scores + (long)z * Ss * Ss;
#pragma unroll
  for (int mt = 0; mt < 8; ++mt)
#pragma unroll
    for (int nt = 0; nt < 4; ++nt)
#pragma unroll
      for (int r = 0; r < 4; ++r) {
        long i = m0 + wm * 128 + mt * 16 + lk * 4 + r;
        int j = n0 + wn * 64 + nt * 16 + lr;
        srow[i * Ss + j] = acc[mt][nt][r] +
                           ubuf[(z << 11) + i] + wbuf[(z << 11) + j];
      }
}

// ---------------------------------------------------------------- softmax
__global__ void __launch_bounds__(256) softmax_rows(const float* __restrict__ scores,
                                                    u16* __restrict__ P) {
  const long r = blockIdx.x;
  const float* row = scores + r * Ss;
  u16* prow = P + r * Ss;
  const int t = threadIdx.x;
  const int wave = t >> 6, lane = t & 63;
  f32x4 v0 = ((const f32x4*)row)[t * 2];
  f32x4 v1 = ((const f32x4*)row)[t * 2 + 1];
  float a[8];
#pragma unroll
  for (int j = 0; j < 4; ++j) { a[j] = v0[j]; a[4 + j] = v1[j]; }

  float m = a[0];
#pragma unroll
  for (int j = 1; j < 8; ++j) m = fmaxf(m, a[j]);
#pragma unroll
  for (int off = 32; off >= 1; off >>= 1) m = fmaxf(m, __shfl_xor(m, off));
  __shared__ float red[4];
  if (lane == 0) red[wave] = m;
  __syncthreads();
  m = fmaxf(fmaxf(red[0], red[1]), fmaxf(red[2], red[3]));

  float e[8];
  float s = 0.f;
#pragma unroll
  for (int j = 0; j < 8; ++j) { e[j] = __expf(a[j] - m); s += e[j]; }
#pragma unroll
  for (int off = 32; off >= 1; off >>= 1) s += __shfl_xor(s, off);
  __syncthreads();
  if (lane == 0) red[wave] = s;
  __syncthreads();
  s = red[0] + red[1] + red[2] + red[3];
  float inv = 1.0f / s;

  u16x8 pk;
#pragma unroll
  for (int j = 0; j < 8; ++j) pk[j] = f2h(e[j] * inv);
  ((u16x8*)prow)[t] = pk;
}

// ---------------------------------------------------------------- PV GEMM
// R19: 256x128 tile, BK=64, NT=32, 2-buffer.
__global__ void __launch_bounds__(256, 1) pv_gemm(const u16* __restrict__ P,
                                                  const u16* __restrict__ vt,
                                                  float* __restrict__ out) {
  __shared__ char lds[98304];
  const int tid = threadIdx.x;
  int bx, by, bz;
  xcd_swz<8, 8, 4>(bx, by, bz);
  const int z = bz;  // batch
  const char* A = (const char*)(P + (long)z * Ss * Ss);
  const char* Bp = (const char*)(vt + (long)z * Dd * Ss);
  const long m0 = (long)by * 256;
  const int n0 = bx * 128;

  const int wave = tid >> 6, lane = tid & 63;
  const int wm = wave >> 1, wn = wave & 1;
  const int lr = lane & 15, lk = lane >> 4;

  f32x4 acc[8][4] = {};
  gemm256_core<32>(A, Bp, m0, n0, (long)Ss * 2, (long)Ss * 2,
                   lds, tid, wm, wn, lane, acc);

  float* orow = out + (long)z * Ss * Dd;
#pragma unroll
  for (int mt = 0; mt < 8; ++mt)
#pragma unroll
    for (int nt = 0; nt < 4; ++nt)
#pragma unroll
      for (int r = 0; r < 4; ++r) {
        long i = m0 + wm * 128 + mt * 16 + lk * 4 + r;
        int e = n0 + wn * 64 + nt * 16 + lr;
        orow[i * Dd + e] = acc[mt][nt][r];
      }
}

// ---------------------------------------------------------------- launch
extern "C" void kernel_launch(void* const* d_in, const int* in_sizes, int n_in,
                              void* d_out, int out_size, void* d_ws, size_t ws_size,
                              hipStream_t stream) {
  const float* x = (const float*)d_in[0];
  const float* Wq = (const float*)d_in[1];
  const float* bq = (const float*)d_in[2];
  const float* Wk = (const float*)d_in[3];
  const float* bk = (const float*)d_in[4];
  const float* Wv = (const float*)d_in[5];
  const float* bv = (const float*)d_in[6];
  float* out = (float*)d_out;

  // workspace carve (~148 MiB). Aliases (writer strictly after aliased reader):
  //   [0,64Mi)   scores          | Gh [0,2Mi) early | wvh [16,18Mi) early
  //   [80,96Mi)  wq digits -> Gpart -> th (each dead before next writer)
  //   [96,128Mi) Pbuf            | xh [96,112Mi): dead before softmax writes P
  //   [128,144Mi) vt
  //   [144,148Mi) wqT0..wkT1
  //   [148Mi..)  gq, gk, ubuf, wbuf, cbuf
  char* p = (char*)d_ws;
  float* scores = (float*)p;
  u16* Gh = (u16*)p;                         // 2MB f16 G^T
  u16* wvh = (u16*)(p + (16L << 20));
  u16* th = (u16*)(p + (80L << 20));         // 16MB f16
  u8* wq0 = (u8*)(p + (80L << 20));          // alias: dead after transpose_w
  u8* wq1 = wq0 + (1L << 20);
  u8* wk0 = wq0 + (2L << 20);
  u8* wk1 = wq0 + (3L << 20);
  float* Gpart = (float*)(p + (80L << 20));  // alias: dead after g_reduce
  u16* Pbuf = (u16*)(p + (96L << 20));
  u16* xh = (u16*)(p + (96L << 20));         // alias: dead before softmax
  u16* vt = (u16*)(p + (128L << 20));
  u8* wqT0 = (u8*)(p + (144L << 20));
  u8* wqT1 = wqT0 + (1L << 20);
  u8* wkT0 = wqT0 + (2L << 20);
  u8* wkT1 = wqT0 + (3L << 20);
  float* gq = (float*)(p + (148L << 20));
  float* gk = gq + 1024;
  float* ubuf = gq + 2048;
  float* wbuf = ubuf + 8192;
  float* cbuf = wbuf + 8192;

  // 1. W digits + Wv f16
  convert_w<<<dim3(3072), dim3(256), 0, stream>>>(Wq, Wk, Wv, wq0, wq1, wk0, wk1, wvh);
  // 2. transpose W digit arrays
  transpose_w<<<dim3(16, 16, 4), dim3(256), 0, stream>>>(
      wq0, wq1, wk0, wk1, wqT0, wqT1, wkT0, wkT1);
  // 3. gq = Wq^T bk, gk = Wk^T bq, c = bq.bk
  gvec_kernel<<<dim3(128), dim3(256), 0, stream>>>(
      wqT0, wqT1, wkT0, wkT1, bq, bk, gq, gk, cbuf);
  // 4. x f16 + u,w row dots
  convert_x<<<dim3(8192), dim3(256), 0, stream>>>(
      x, gq, gk, cbuf, xh, ubuf, wbuf);
  // 5. v projection (f16, 256x128 tile, BK=64)
  v_gemm<<<dim3(Dd / 128, Mtot / 256), dim3(256), 0, stream>>>(xh, wvh, bv, vt);
  // 6. G partials (K-split 4, exact i8), over wq row-major digits (dead)
  g_part<<<dim3(8, 8, 4), dim3(256), 0, stream>>>(wqT0, wqT1, wkT0, wkT1, Gpart);
  // 7. reduce -> f16 Gh
  g_reduce<<<dim3(1024), dim3(256), 0, stream>>>(Gpart, Gh);
  // 8. t = x G (f16 GEMM, 256x128 tile, BK=64)
  t_gemm<<<dim3(Dd / 128, Mtot / 256), dim3(256), 0, stream>>>(xh, Gh, th);
  // 9. scores = th x^T + u + w (f16 GEMM, 256x128 tile, BK=64)
  score_gemm<<<dim3(Ss / 128, Ss / 256, Bb), dim3(256), 0, stream>>>(
      th, xh, ubuf, wbuf, scores);
  // 10. softmax rows -> dense P (overwrites xh, dead)
  softmax_rows<<<dim3(Bb * Ss), dim3(256), 0, stream>>>(scores, Pbuf);
  // 11. out = P @ v (256x128 tile, BK=64)
  pv_gemm<<<dim3(Dd / 128, Ss / 256, Bb), dim3(256), 0, stream>>>(Pbuf, vt, out);
}

// Round 14
// 301.760 us; speedup vs baseline: 1.0694x; 1.0694x over previous
//
#include <hip/hip_runtime.h>

// SelfAttention: B=4, S=2048, D=1024, fp32 in/out.
// q=x@Wq^T+bq, k=..., v=...; out = softmax(q k^T) @ v   (no 1/sqrt(d) scale)
//
// R11: scores = x G x^T + u 1^T + 1 w^T (G = Wq^T Wk precomputed; one
//   projection GEMM t = x G instead of two; biases exact f32 epilogue adds).
// Carried: R8 fragment-linear LDS (bank conflicts 0), R9 counted-vmcnt +
//   raw s_barrier (T4), R10 XCD swizzle, R13/R15 f16 GEMMs (absmax 0.1016
//   accepted), R16 depth-2 3-buffer pipeline.
// R17/R18 (validated, BEST = 300.8us): 256x128 tile / wave-tile 128x64 =
//   the per-MFMA LDS/barrier ratio lever, at 2 blocks/CU (score) with
//   3-buffer BK=32 depth-2 pipeline.
// R19/R20 POST-MORTEM (reverted): BK=64 regressed score 59->68us. Cause:
//   occupancy 2->1 block/CU killed inter-block overlap (the R3/R6 lesson)
//   and VGPR 100->180 from the wider stage. The 2-phase template's barrier
//   residual cannot be amortized by coarser K-steps at this LDS budget;
//   the next real lever is the 8-phase interleave (new sync structure, not
//   attempted blind). This file is the R11/R18 best-known configuration.

#define Bb 4
#define Ss 2048
#define Dd 1024
#define Mtot 8192  // B*S

typedef _Float16 f16x8 __attribute__((ext_vector_type(8)));
typedef float f32x4 __attribute__((ext_vector_type(4)));
typedef int i32x4 __attribute__((ext_vector_type(4)));
typedef signed char i8x16 __attribute__((ext_vector_type(16)));
typedef unsigned short u16;
typedef unsigned int u32;
typedef unsigned char u8;
typedef u16 u16x8 __attribute__((ext_vector_type(8)));
typedef u16 u16x4 __attribute__((ext_vector_type(4)));
typedef void __attribute__((address_space(1))) gvoid_t;
typedef void __attribute__((address_space(3))) svoid_t;

// ---- W digit scales (powers of two) ----
#define WC 1.953125e-3f               // 2^-9
#define WCI 512.f
#define WFI 131072.f
#define W1S 7.62939453125e-6f         // 2^-17
// G = Wq^T Wk accumulator scales
#define SG00 3.814697265625e-6f       // 2^-18
#define SG01 1.4901161193847656e-8f   // 2^-26
#define SG11 5.820766091346741e-11f   // 2^-34

__device__ __forceinline__ void gl_lds16(const void* g, void* l) {
  __builtin_amdgcn_global_load_lds((gvoid_t*)g, (svoid_t*)l, 16, 0, 0);
}

__device__ __forceinline__ u16 f2h(float f) {
  return __builtin_bit_cast(u16, (_Float16)f);
}
__device__ __forceinline__ f16x8 frag_ld_h(const char* p) {
  u16x8 v = *(const u16x8*)p;
  return __builtin_bit_cast(f16x8, v);
}
__device__ __forceinline__ f32x4 mfma_f16(f16x8 a, f16x8 b, f32x4 c) {
  return __builtin_amdgcn_mfma_f32_16x16x32_f16(a, b, c, 0, 0, 0);
}
__device__ __forceinline__ i32x4 mfma_i8(i32x4 a, i32x4 b, i32x4 c) {
  return __builtin_amdgcn_mfma_i32_16x16x64_i8(a, b, c, 0, 0, 0);
}
// split v into two clamped i8 digits: v ~= d0*cs + d1*(1/fi)
__device__ __forceinline__ void dig2(float v, float cs, float ci, float fi,
                                     int& d0, int& d1) {
  float t = fminf(fmaxf(v * ci, -127.f), 127.f);
  d0 = __float2int_rn(t);
  float res = v - (float)d0 * cs;
  float u = fminf(fmaxf(res * fi, -127.f), 127.f);
  d1 = __float2int_rn(u);
}

// T1: bijective XCD-aware block swizzle (pow2 grids, N%8==0).
template <int GX, int GY, int GZ>
__device__ __forceinline__ void xcd_swz(int& bx, int& by, int& bz) {
  constexpr int N = GX * GY * GZ;
  int flat = (int)blockIdx.x + GX * ((int)blockIdx.y + GY * (int)blockIdx.z);
  int s = (flat & 7) * (N >> 3) + (flat >> 3);
  bx = s & (GX - 1);
  by = (s / GX) & (GY - 1);
  bz = s / (GX * GY);
}

// T4 pipeline sync: wait with N loads still in flight, then raw barrier.
__device__ __forceinline__ void wait_bar_keep12() {
  asm volatile("s_waitcnt vmcnt(12)" ::: "memory");
  __builtin_amdgcn_s_barrier();
  __builtin_amdgcn_sched_barrier(0);
}
__device__ __forceinline__ void wait_bar_keep8() {
  asm volatile("s_waitcnt vmcnt(8)" ::: "memory");
  __builtin_amdgcn_s_barrier();
  __builtin_amdgcn_sched_barrier(0);
}
__device__ __forceinline__ void wait_bar_keep6() {
  asm volatile("s_waitcnt vmcnt(6)" ::: "memory");
  __builtin_amdgcn_s_barrier();
  __builtin_amdgcn_sched_barrier(0);
}
__device__ __forceinline__ void wait_bar_drain() {
  asm volatile("s_waitcnt vmcnt(0)" ::: "memory");
  __builtin_amdgcn_s_barrier();
  __builtin_amdgcn_sched_barrier(0);
}
__device__ __forceinline__ void end_bar() {
  __builtin_amdgcn_sched_barrier(0);
  __builtin_amdgcn_s_barrier();
}

// Fragment-linear stager (R8): LDS dest lane-linear, GLOBAL source permuted so
// each 16-row subtile lands as [chunk-group h][chunk lk][row lr]; MFMA fragment
// read is subtile_base + h*1024 + lane*16 -> conflict-free.
template <int ROUNDS, int C>
__device__ __forceinline__ void stageF(const char* g, long row0, long ldb,
                                       long k0b, char* l, int tid) {
#pragma unroll
  for (int r = 0; r < ROUNDS; ++r) {
    int s = r * 256 + tid;
    int sub = s / (16 * C);
    int t = s % (16 * C);
    int h = t >> 6;
    int lk = (t >> 4) & 3;
    int lr = t & 15;
    gl_lds16(g + (row0 + sub * 16 + lr) * ldb + k0b + (h * 4 + lk) * 16,
             l + s * 16);
  }
}

// R17/R18: shared f16 GEMM core, 256x128 tile, 4 waves (2M x 2N), wave-tile
// 128x64 (acc 8x4), BK=32, 3-buffer depth-2 counted-vmcnt pipeline.
// LDS layout per buffer (24KB): A 256x32 f16 (16KB) | B 128x32 f16 (8KB).
template <int NT>
__device__ __forceinline__ void gemm256_core(
    const char* A, const char* B, long m0, long n0, long lda, long ldb,
    char* lds, int tid, int wm, int wn, int lane, f32x4 (&acc)[8][4]) {
  auto stage = [&](char* L, int t) {  // 6 gl_lds per thread
    stageF<4, 4>(A, m0, lda, (long)t * 64, L, tid);          // 256x32
    stageF<2, 4>(B, n0, ldb, (long)t * 64, L + 16384, tid);  // 128x32
  };
  auto compute = [&](const char* L) {
    f16x8 af[8], bfr[4];
#pragma unroll
    for (int i = 0; i < 8; ++i)
      af[i] = frag_ld_h(L + (wm * 8 + i) * 1024 + lane * 16);
#pragma unroll
    for (int i = 0; i < 4; ++i)
      bfr[i] = frag_ld_h(L + 16384 + (wn * 4 + i) * 1024 + lane * 16);
    __builtin_amdgcn_s_setprio(1);
#pragma unroll
    for (int mt = 0; mt < 8; ++mt)
#pragma unroll
      for (int nt = 0; nt < 4; ++nt)
        acc[mt][nt] = mfma_f16(af[mt], bfr[nt], acc[mt][nt]);
    __builtin_amdgcn_s_setprio(0);
  };

  char* L0 = lds;
  char* L1 = lds + 24576;
  char* L2 = lds + 49152;
  stage(L0, 0);
  stage(L1, 1);
  for (int t = 0; t < NT - 2; ++t) {
    stage(L2, t + 2);
    wait_bar_keep12();  // 18 outstanding -> 12 == stage(t) landed
    compute(L0);
    end_bar();
    char* tmp = L0; L0 = L1; L1 = L2; L2 = tmp;
  }
  wait_bar_keep6();     // stage(NT-2) landed
  compute(L0);
  end_bar();
  wait_bar_drain();     // stage(NT-1) landed
  compute(L1);
}

// ---------------------------------------------------------------- convert W
__global__ void __launch_bounds__(256) convert_w(
    const float* __restrict__ Wq, const float* __restrict__ Wk,
    const float* __restrict__ Wv,
    u8* __restrict__ wq0, u8* __restrict__ wq1,
    u8* __restrict__ wk0, u8* __restrict__ wk1, u16* __restrict__ wvh) {
  long b = blockIdx.x;
  if (b < 2048) {
    int which = (int)(b >> 10);  // 0=q, 1=k
    const float* src = which ? Wk : Wq;
    u8* o0 = which ? wk0 : wq0;
    u8* o1 = which ? wk1 : wq1;
    long i = (b & 1023) * 256 + threadIdx.x;
    f32x4 v = ((const f32x4*)src)[i];
    u32 p0 = 0, p1 = 0;
#pragma unroll
    for (int j = 0; j < 4; ++j) {
      int d0, d1;
      dig2(v[j], WC, WCI, WFI, d0, d1);
      p0 |= ((u32)(d0 & 255)) << (8 * j);
      p1 |= ((u32)(d1 & 255)) << (8 * j);
    }
    ((u32*)o0)[i] = p0;
    ((u32*)o1)[i] = p1;
  } else {
    long i = (b - 2048) * 256 + threadIdx.x;
    f32x4 v = ((const f32x4*)Wv)[i];
    u16x4 h;
#pragma unroll
    for (int j = 0; j < 4; ++j) h[j] = f2h(v[j]);
    ((u16x4*)wvh)[i] = h;
  }
}

// ---------------------------------------------------------------- transpose W digits
__global__ void __launch_bounds__(256) transpose_w(
    const u8* __restrict__ wq0, const u8* __restrict__ wq1,
    const u8* __restrict__ wk0, const u8* __restrict__ wk1,
    u8* __restrict__ wqT0, u8* __restrict__ wqT1,
    u8* __restrict__ wkT0, u8* __restrict__ wkT1) {
  __shared__ u8 T[64][68];
  int a = blockIdx.z;
  const u8* src = a == 0 ? wq0 : a == 1 ? wq1 : a == 2 ? wk0 : wk1;
  u8* dst = a == 0 ? wqT0 : a == 1 ? wqT1 : a == 2 ? wkT0 : wkT1;
  int bi = blockIdx.y, bj = blockIdx.x;
  int t = threadIdx.x, r = t >> 2, c4 = t & 3;
  const u32* s = (const u32*)(src + (long)(bi * 64 + r) * 1024 + bj * 64 + c4 * 16);
  u32 v0 = s[0], v1 = s[1], v2 = s[2], v3 = s[3];
  u32* trow = (u32*)&T[r][c4 * 16];
  trow[0] = v0; trow[1] = v1; trow[2] = v2; trow[3] = v3;
  __syncthreads();
  u32 o[4] = {0, 0, 0, 0};
#pragma unroll
  for (int j = 0; j < 16; ++j)
    o[j >> 2] |= ((u32)T[c4 * 16 + j][r]) << (8 * (j & 3));
  u32* d = (u32*)(dst + (long)(bj * 64 + r) * 1024 + bi * 64 + c4 * 16);
  d[0] = o[0]; d[1] = o[1]; d[2] = o[2]; d[3] = o[3];
}

// ---------------------------------------------------------------- gvec
__global__ void __launch_bounds__(256) gvec_kernel(
    const u8* __restrict__ wqT0, const u8* __restrict__ wqT1,
    const u8* __restrict__ wkT0, const u8* __restrict__ wkT1,
    const float* __restrict__ bq, const float* __restrict__ bk,
    float* __restrict__ gq, float* __restrict__ gk, float* __restrict__ cbuf) {
  __shared__ float sbq[1024], sbk[1024];
  int tid = threadIdx.x;
  ((f32x4*)sbq)[tid] = ((const f32x4*)bq)[tid];
  ((f32x4*)sbk)[tid] = ((const f32x4*)bk)[tid];
  __syncthreads();
  int wave = tid >> 6, lane = tid & 63;
#pragma unroll
  for (int rr = 0; rr < 2; ++rr) {
    int d = blockIdx.x * 8 + wave * 2 + rr;
    i8x16 a0 = *(const i8x16*)(wqT0 + (long)d * 1024 + lane * 16);
    i8x16 a1 = *(const i8x16*)(wqT1 + (long)d * 1024 + lane * 16);
    i8x16 c0 = *(const i8x16*)(wkT0 + (long)d * 1024 + lane * 16);
    i8x16 c1 = *(const i8x16*)(wkT1 + (long)d * 1024 + lane * 16);
    float sq = 0.f, sk = 0.f;
#pragma unroll
    for (int j = 0; j < 16; ++j) {
      sq += ((float)a0[j] * WC + (float)a1[j] * W1S) * sbk[lane * 16 + j];
      sk += ((float)c0[j] * WC + (float)c1[j] * W1S) * sbq[lane * 16 + j];
    }
#pragma unroll
    for (int off = 32; off >= 1; off >>= 1) {
      sq += __shfl_xor(sq, off);
      sk += __shfl_xor(sk, off);
    }
    if (!lane) { gq[d] = sq; gk[d] = sk; }
  }
  if (blockIdx.x == 0 && wave == 0) {
    float c = 0.f;
#pragma unroll
    for (int j = 0; j < 16; ++j) c += sbq[lane * 16 + j] * sbk[lane * 16 + j];
#pragma unroll
    for (int off = 32; off >= 1; off >>= 1) c += __shfl_xor(c, off);
    if (!lane) cbuf[0] = c;
  }
}

// ---------------------------------------------------------------- convert x
// f16 (for t/v/score GEMMs) + row dots u, w.
__global__ void __launch_bounds__(256) convert_x(
    const float* __restrict__ x, const float* __restrict__ gq,
    const float* __restrict__ gk, const float* __restrict__ cbuf,
    u16* __restrict__ xh, float* __restrict__ ubuf, float* __restrict__ wbuf) {
  long b = blockIdx.x;
  int tid = threadIdx.x;
  long i = b * 256 + tid;
  f32x4 v = ((const f32x4*)x)[i];
  u16x4 h;
#pragma unroll
  for (int j = 0; j < 4; ++j) h[j] = f2h(v[j]);
  ((u16x4*)xh)[i] = h;

  f32x4 g4 = ((const f32x4*)gq)[tid];
  f32x4 k4 = ((const f32x4*)gk)[tid];
  float pu = v[0] * g4[0] + v[1] * g4[1] + v[2] * g4[2] + v[3] * g4[3];
  float pw = v[0] * k4[0] + v[1] * k4[1] + v[2] * k4[2] + v[3] * k4[3];
#pragma unroll
  for (int off = 32; off >= 1; off >>= 1) {
    pu += __shfl_xor(pu, off);
    pw += __shfl_xor(pw, off);
  }
  __shared__ float ru[4], rw[4];
  int wave = tid >> 6, lane = tid & 63;
  if (!lane) { ru[wave] = pu; rw[wave] = pw; }
  __syncthreads();
  if (!tid) {
    ubuf[b] = ru[0] + ru[1] + ru[2] + ru[3] + cbuf[0];
    wbuf[b] = rw[0] + rw[1] + rw[2] + rw[3];
  }
}

// ---------------------------------------------------------------- G partial GEMM
__global__ void __launch_bounds__(256, 2) g_part(
    const u8* __restrict__ wqT0, const u8* __restrict__ wqT1,
    const u8* __restrict__ wkT0, const u8* __restrict__ wkT1,
    float* __restrict__ Gpart) {
  __shared__ char lds[65536];
  const int tid = threadIdx.x;
  const int bx = blockIdx.x, by = blockIdx.y, bz = blockIdx.z;
  const long m0 = (long)by * 128;
  const int n0 = bx * 128;
  const int k00 = bz * 256;
  const int wave = tid >> 6, lane = tid & 63;
  const int wm = wave >> 1, wn = wave & 1;
  const int lr = lane & 15, lk = lane >> 4;

  i32x4 accM[4][4] = {};
  i32x4 accX[4][4] = {};
  i32x4 accY[4][4] = {};

  auto stage = [&](char* L, int kk) {
    stageF<2, 4>((const char*)wqT0, m0, 1024, kk, L + 0, tid);
    stageF<2, 4>((const char*)wqT1, m0, 1024, kk, L + 8192, tid);
    stageF<2, 4>((const char*)wkT0, n0, 1024, kk, L + 16384, tid);
    stageF<2, 4>((const char*)wkT1, n0, 1024, kk, L + 24576, tid);
  };
  auto compute = [&](const char* L) {
    i32x4 b0[4], b1[4];
#pragma unroll
    for (int nt = 0; nt < 4; ++nt) {
      int rb = (wn * 4 + nt) * 1024 + lane * 16;
      b0[nt] = *(const i32x4*)(L + 16384 + rb);
      b1[nt] = *(const i32x4*)(L + 24576 + rb);
    }
    __builtin_amdgcn_s_setprio(1);
#pragma unroll
    for (int mt = 0; mt < 4; ++mt) {
      int ra = (wm * 4 + mt) * 1024 + lane * 16;
      i32x4 a0 = *(const i32x4*)(L + ra);
      i32x4 a1 = *(const i32x4*)(L + 8192 + ra);
#pragma unroll
      for (int nt = 0; nt < 4; ++nt) {
        accM[mt][nt] = mfma_i8(a0, b0[nt], accM[mt][nt]);
        accX[mt][nt] = mfma_i8(a0, b1[nt], accX[mt][nt]);
        accX[mt][nt] = mfma_i8(a1, b0[nt], accX[mt][nt]);
        accY[mt][nt] = mfma_i8(a1, b1[nt], accY[mt][nt]);
      }
    }
    __builtin_amdgcn_s_setprio(0);
  };

  stage(lds, k00);
  for (int t = 0; t < 3; ++t) {
    char* L = lds + (t & 1) * 32768;
    stage(lds + ((t + 1) & 1) * 32768, k00 + (t + 1) * 64);
    wait_bar_keep8();
    compute(L);
    end_bar();
  }
  {
    char* L = lds + 32768;
    wait_bar_drain();
    compute(L);
  }

#pragma unroll
  for (int mt = 0; mt < 4; ++mt)
#pragma unroll
    for (int nt = 0; nt < 4; ++nt) {
      int e = n0 + wn * 64 + nt * 16 + lr;
      int gmb = (int)m0 + wm * 64 + mt * 16 + lk * 4;
      f32x4 o;
#pragma unroll
      for (int r = 0; r < 4; ++r)
        o[r] = (float)accM[mt][nt][r] * SG00 + (float)accX[mt][nt][r] * SG01 +
               (float)accY[mt][nt][r] * SG11;
      *(f32x4*)(Gpart + ((long)bz << 20) + (long)e * 1024 + gmb) = o;
    }
}

// ---------------------------------------------------------------- G reduce -> f16
__global__ void __launch_bounds__(256) g_reduce(const float* __restrict__ Gpart,
                                                u16* __restrict__ Gh) {
  int n = blockIdx.x, tid = threadIdx.x;
  long o = (long)n * 1024 + tid * 4;
  f32x4 v = *(const f32x4*)(Gpart + o);
  f32x4 v1 = *(const f32x4*)(Gpart + (1L << 20) + o);
  f32x4 v2 = *(const f32x4*)(Gpart + (2L << 20) + o);
  f32x4 v3 = *(const f32x4*)(Gpart + (3L << 20) + o);
  u16x4 h;
#pragma unroll
  for (int j = 0; j < 4; ++j) h[j] = f2h(v[j] + v1[j] + v2[j] + v3[j]);
  ((u16x4*)Gh)[n * 256 + tid] = h;
}

// ---------------------------------------------------------------- t GEMM (f16, t = x G)
// 256x128 tile, wave-tile 128x64 (R18, validated).
__global__ void __launch_bounds__(256, 2) t_gemm(
    const u16* __restrict__ xh, const u16* __restrict__ Gh,
    u16* __restrict__ th) {
  __shared__ char lds[73728];
  const int tid = threadIdx.x;
  int bx, by, bz;
  xcd_swz<8, 32, 1>(bx, by, bz);
  const long m0 = (long)by * 256;
  const int n0 = bx * 128;
  const int wave = tid >> 6, lane = tid & 63;
  const int wm = wave >> 1, wn = wave & 1;
  const int lr = lane & 15, lk = lane >> 4;

  f32x4 acc[8][4] = {};
  gemm256_core<32>((const char*)xh, (const char*)Gh, m0, n0,
                   (long)Dd * 2, (long)Dd * 2, lds, tid, wm, wn, lane, acc);

#pragma unroll
  for (int mt = 0; mt < 8; ++mt)
#pragma unroll
    for (int nt = 0; nt < 4; ++nt)
#pragma unroll
      for (int r = 0; r < 4; ++r) {
        long gm = m0 + wm * 128 + mt * 16 + lk * 4 + r;
        int e = n0 + wn * 64 + nt * 16 + lr;
        th[gm * Dd + e] = f2h(acc[mt][nt][r]);
      }
}

// ---------------------------------------------------------------- v GEMM (f16)
// 256x128 tile, wave-tile 128x64 (R18, validated).
__global__ void __launch_bounds__(256, 2) v_gemm(
    const u16* __restrict__ xh, const u16* __restrict__ wvh,
    const float* __restrict__ bv, u16* __restrict__ vt) {
  __shared__ char lds[73728];
  const int tid = threadIdx.x;
  int bx, by, bz;
  xcd_swz<8, 32, 1>(bx, by, bz);
  const long m0 = (long)by * 256;
  const int n0 = bx * 128;
  const int wave = tid >> 6, lane = tid & 63;
  const int wm = wave >> 1, wn = wave & 1;
  const int lr = lane & 15, lk = lane >> 4;

  f32x4 acc[8][4] = {};
  gemm256_core<32>((const char*)xh, (const char*)wvh, m0, n0,
                   (long)Dd * 2, (long)Dd * 2, lds, tid, wm, wn, lane, acc);

#pragma unroll
  for (int mt = 0; mt < 8; ++mt)
#pragma unroll
    for (int nt = 0; nt < 4; ++nt)
#pragma unroll
      for (int r = 0; r < 4; ++r) {
        long gm = m0 + wm * 128 + mt * 16 + lk * 4 + r;
        int e = n0 + wn * 64 + nt * 16 + lr;
        float v = acc[mt][nt][r] + bv[e];
        long b = gm >> 11, s = gm & 2047;
        vt[(b * Dd + e) * (long)Ss + s] = f2h(v);
      }
}

// ---------------------------------------------------------------- scores GEMM (f16)
// 256x128 tile, wave-tile 128x64, 3-buffer depth-2 (R17, validated).
__global__ void __launch_bounds__(256, 2) score_gemm(
    const u16* __restrict__ th, const u16* __restrict__ xh,
    const float* __restrict__ ubuf, const float* __restrict__ wbuf,
    float* __restrict__ scores) {
  __shared__ char lds[73728];
  const int tid = threadIdx.x;
  int bx, by, bz;
  xcd_swz<16, 8, 4>(bx, by, bz);
  const int z = bz;  // batch
  const long base = (long)z * Ss * Dd * 2;  // byte offset
  const long m0 = (long)by * 256;
  const int n0 = bx * 128;
  const int wave = tid >> 6, lane = tid & 63;
  const int wm = wave >> 1, wn = wave & 1;
  const int lr = lane & 15, lk = lane >> 4;

  f32x4 acc[8][4] = {};
  gemm256_core<32>((const char*)th + base, (const char*)xh + base, m0, n0,
                   (long)Dd * 2, (long)Dd * 2, lds, tid, wm, wn, lane, acc);

  float* srow = scores + (long)z * Ss * Ss;
#pragma unroll
  for (int mt = 0; mt < 8; ++mt)
#pragma unroll
    for (int nt = 0; nt < 4; ++nt)
#pragma unroll
      for (int r = 0; r < 4; ++r) {
        long i = m0 + wm * 128 + mt * 16 + lk * 4 + r;
        int j = n0 + wn * 64 + nt * 16 + lr;
        srow[i * Ss + j] = acc[mt][nt][r] +
                           ubuf[(z << 11) + i] + wbuf[(z << 11) + j];
      }
}

// ---------------------------------------------------------------- softmax
__global__ void __launch_bounds__(256) softmax_rows(const float* __restrict__ scores,
                                                    u16* __restrict__ P) {
  const long r = blockIdx.x;
  const float* row = scores + r * Ss;
  u16* prow = P + r * Ss;
  const int t = threadIdx.x;
  const int wave = t >> 6, lane = t & 63;
  f32x4 v0 = ((const f32x4*)row)[t * 2];
  f32x4 v1 = ((const f32x4*)row)[t * 2 + 1];
  float a[8];
#pragma unroll
  for (int j = 0; j < 4; ++j) { a[j] = v0[j]; a[4 + j] = v1[j]; }

  float m = a[0];
#pragma unroll
  for (int j = 1; j < 8; ++j) m = fmaxf(m, a[j]);
#pragma unroll
  for (int off = 32; off >= 1; off >>= 1) m = fmaxf(m, __shfl_xor(m, off));
  __shared__ float red[4];
  if (lane == 0) red[wave] = m;
  __syncthreads();
  m = fmaxf(fmaxf(red[0], red[1]), fmaxf(red[2], red[3]));

  float e[8];
  float s = 0.f;
#pragma unroll
  for (int j = 0; j < 8; ++j) { e[j] = __expf(a[j] - m); s += e[j]; }
#pragma unroll
  for (int off = 32; off >= 1; off >>= 1) s += __shfl_xor(s, off);
  __syncthreads();
  if (lane == 0) red[wave] = s;
  __syncthreads();
  s = red[0] + red[1] + red[2] + red[3];
  float inv = 1.0f / s;

  u16x8 pk;
#pragma unroll
  for (int j = 0; j < 8; ++j) pk[j] = f2h(e[j] * inv);
  ((u16x8*)prow)[t] = pk;
}

// ---------------------------------------------------------------- PV GEMM
// 256x128 tile, wave-tile 128x64, NT=64 (R18, validated).
__global__ void __launch_bounds__(256, 2) pv_gemm(const u16* __restrict__ P,
                                                  const u16* __restrict__ vt,
                                                  float* __restrict__ out) {
  __shared__ char lds[73728];
  const int tid = threadIdx.x;
  int bx, by, bz;
  xcd_swz<8, 8, 4>(bx, by, bz);
  const int z = bz;  // batch
  const char* A = (const char*)(P + (long)z * Ss * Ss);
  const char* Bp = (const char*)(vt + (long)z * Dd * Ss);
  const long m0 = (long)by * 256;
  const int n0 = bx * 128;

  const int wave = tid >> 6, lane = tid & 63;
  const int wm = wave >> 1, wn = wave & 1;
  const int lr = lane & 15, lk = lane >> 4;

  f32x4 acc[8][4] = {};
  gemm256_core<64>(A, Bp, m0, n0, (long)Ss * 2, (long)Ss * 2,
                   lds, tid, wm, wn, lane, acc);

  float* orow = out + (long)z * Ss * Dd;
#pragma unroll
  for (int mt = 0; mt < 8; ++mt)
#pragma unroll
    for (int nt = 0; nt < 4; ++nt)
#pragma unroll
      for (int r = 0; r < 4; ++r) {
        long i = m0 + wm * 128 + mt * 16 + lk * 4 + r;
        int e = n0 + wn * 64 + nt * 16 + lr;
        orow[i * Dd + e] = acc[mt][nt][r];
      }
}

// ---------------------------------------------------------------- launch
extern "C" void kernel_launch(void* const* d_in, const int* in_sizes, int n_in,
                              void* d_out, int out_size, void* d_ws, size_t ws_size,
                              hipStream_t stream) {
  const float* x = (const float*)d_in[0];
  const float* Wq = (const float*)d_in[1];
  const float* bq = (const float*)d_in[2];
  const float* Wk = (const float*)d_in[3];
  const float* bk = (const float*)d_in[4];
  const float* Wv = (const float*)d_in[5];
  const float* bv = (const float*)d_in[6];
  float* out = (float*)d_out;

  // workspace carve (~148 MiB). Aliases (writer strictly after aliased reader):
  //   [0,64Mi)   scores          | Gh [0,2Mi) early | wvh [16,18Mi) early
  //   [80,96Mi)  wq digits -> Gpart -> th (each dead before next writer)
  //   [96,128Mi) Pbuf            | xh [96,112Mi): dead before softmax writes P
  //   [128,144Mi) vt
  //   [144,148Mi) wqT0..wkT1
  //   [148Mi..)  gq, gk, ubuf, wbuf, cbuf
  char* p = (char*)d_ws;
  float* scores = (float*)p;
  u16* Gh = (u16*)p;                         // 2MB f16 G^T
  u16* wvh = (u16*)(p + (16L << 20));
  u16* th = (u16*)(p + (80L << 20));         // 16MB f16
  u8* wq0 = (u8*)(p + (80L << 20));          // alias: dead after transpose_w
  u8* wq1 = wq0 + (1L << 20);
  u8* wk0 = wq0 + (2L << 20);
  u8* wk1 = wq0 + (3L << 20);
  float* Gpart = (float*)(p + (80L << 20));  // alias: dead after g_reduce
  u16* Pbuf = (u16*)(p + (96L << 20));
  u16* xh = (u16*)(p + (96L << 20));         // alias: dead before softmax
  u16* vt = (u16*)(p + (128L << 20));
  u8* wqT0 = (u8*)(p + (144L << 20));
  u8* wqT1 = wqT0 + (1L << 20);
  u8* wkT0 = wqT0 + (2L << 20);
  u8* wkT1 = wqT0 + (3L << 20);
  float* gq = (float*)(p + (148L << 20));
  float* gk = gq + 1024;
  float* ubuf = gq + 2048;
  float* wbuf = ubuf + 8192;
  float* cbuf = wbuf + 8192;

  // 1. W digits + Wv f16
  convert_w<<<dim3(3072), dim3(256), 0, stream>>>(Wq, Wk, Wv, wq0, wq1, wk0, wk1, wvh);
  // 2. transpose W digit arrays
  transpose_w<<<dim3(16, 16, 4), dim3(256), 0, stream>>>(
      wq0, wq1, wk0, wk1, wqT0, wqT1, wkT0, wkT1);
  // 3. gq = Wq^T bk, gk = Wk^T bq, c = bq.bk
  gvec_kernel<<<dim3(128), dim3(256), 0, stream>>>(
      wqT0, wqT1, wkT0, wkT1, bq, bk, gq, gk, cbuf);
  // 4. x f16 + u,w row dots
  convert_x<<<dim3(8192), dim3(256), 0, stream>>>(
      x, gq, gk, cbuf, xh, ubuf, wbuf);
  // 5. v projection (f16, 256x128 tile)
  v_gemm<<<dim3(Dd / 128, Mtot / 256), dim3(256), 0, stream>>>(xh, wvh, bv, vt);
  // 6. G partials (K-split 4, exact i8), over wq row-major digits (dead)
  g_part<<<dim3(8, 8, 4), dim3(256), 0, stream>>>(wqT0, wqT1, wkT0, wkT1, Gpart);
  // 7. reduce -> f16 Gh
  g_reduce<<<dim3(1024), dim3(256), 0, stream>>>(Gpart, Gh);
  // 8. t = x G (f16 GEMM, 256x128 tile; th over Gpart which is dead)
  t_gemm<<<dim3(Dd / 128, Mtot / 256), dim3(256), 0, stream>>>(xh, Gh, th);
  // 9. scores = th x^T + u + w (f16 GEMM, 256x128 tile)
  score_gemm<<<dim3(Ss / 128, Ss / 256, Bb), dim3(256), 0, stream>>>(
      th, xh, ubuf, wbuf, scores);
  // 10. softmax rows -> dense P (overwrites xh, dead)
  softmax_rows<<<dim3(Bb * Ss), dim3(256), 0, stream>>>(scores, Pbuf);
  // 11. out = P @ v (256x128 tile)
  pv_gemm<<<dim3(Dd / 128, Ss / 256, Bb), dim3(256), 0, stream>>>(Pbuf, vt, out);
}

// Round 15
// 299.629 us; speedup vs baseline: 1.0770x; 1.0071x over previous
//
#include <hip/hip_runtime.h>

// SelfAttention: B=4, S=2048, D=1024, fp32 in/out.
// q=x@Wq^T+bq, k=..., v=...; out = softmax(q k^T) @ v   (no 1/sqrt(d) scale)
//
// R11: scores = x G x^T + u 1^T + 1 w^T (G = Wq^T Wk precomputed; one
//   projection GEMM t = x G instead of two; biases exact f32 epilogue adds).
// Carried: R8 fragment-linear LDS (bank conflicts 0), R9 counted-vmcnt +
//   raw s_barrier (T4), R10 XCD swizzle, R13/R15 f16 GEMMs (absmax 0.1016
//   accepted), R17/R18 256x128 tile / wave-tile 128x64 with 3-buffer BK=32
//   depth-2 pipeline at 2 blocks/CU (validated best, ~301us).
// R19/R20 (reverted): BK=64 regressed (occupancy 2->1 block/CU killed
//   inter-block overlap; VGPR 100->180). 2-phase barrier residual can't be
//   amortized by coarser K-steps; 8-phase rewrite deemed too risky blind.
// R21 CONSOLIDATION (no GEMM-core changes):
//   - convert_w + transpose_w fused into convert_wt (row-major W digits had
//     no reader but the transpose; saves 8MB round-trip + a launch).
//   - t_gemm + v_gemm merged into tv_gemm (grid z=2): both read the same
//     16MB xh A-matrix; merged they co-reside 2 blocks/CU, share xh in L2,
//     and pay one dispatch tail instead of two. Launches 11 -> 9.

#define Bb 4
#define Ss 2048
#define Dd 1024
#define Mtot 8192  // B*S

typedef _Float16 f16x8 __attribute__((ext_vector_type(8)));
typedef float f32x4 __attribute__((ext_vector_type(4)));
typedef int i32x4 __attribute__((ext_vector_type(4)));
typedef signed char i8x16 __attribute__((ext_vector_type(16)));
typedef unsigned short u16;
typedef unsigned int u32;
typedef unsigned char u8;
typedef u16 u16x8 __attribute__((ext_vector_type(8)));
typedef u16 u16x4 __attribute__((ext_vector_type(4)));
typedef void __attribute__((address_space(1))) gvoid_t;
typedef void __attribute__((address_space(3))) svoid_t;

// ---- W digit scales (powers of two) ----
#define WC 1.953125e-3f               // 2^-9
#define WCI 512.f
#define WFI 131072.f
#define W1S 7.62939453125e-6f         // 2^-17
// G = Wq^T Wk accumulator scales
#define SG00 3.814697265625e-6f       // 2^-18
#define SG01 1.4901161193847656e-8f   // 2^-26
#define SG11 5.820766091346741e-11f   // 2^-34

__device__ __forceinline__ void gl_lds16(const void* g, void* l) {
  __builtin_amdgcn_global_load_lds((gvoid_t*)g, (svoid_t*)l, 16, 0, 0);
}

__device__ __forceinline__ u16 f2h(float f) {
  return __builtin_bit_cast(u16, (_Float16)f);
}
__device__ __forceinline__ f16x8 frag_ld_h(const char* p) {
  u16x8 v = *(const u16x8*)p;
  return __builtin_bit_cast(f16x8, v);
}
__device__ __forceinline__ f32x4 mfma_f16(f16x8 a, f16x8 b, f32x4 c) {
  return __builtin_amdgcn_mfma_f32_16x16x32_f16(a, b, c, 0, 0, 0);
}
__device__ __forceinline__ i32x4 mfma_i8(i32x4 a, i32x4 b, i32x4 c) {
  return __builtin_amdgcn_mfma_i32_16x16x64_i8(a, b, c, 0, 0, 0);
}
// split v into two clamped i8 digits: v ~= d0*cs + d1*(1/fi)
__device__ __forceinline__ void dig2(float v, float cs, float ci, float fi,
                                     int& d0, int& d1) {
  float t = fminf(fmaxf(v * ci, -127.f), 127.f);
  d0 = __float2int_rn(t);
  float res = v - (float)d0 * cs;
  float u = fminf(fmaxf(res * fi, -127.f), 127.f);
  d1 = __float2int_rn(u);
}

// T1: bijective XCD-aware block swizzle (pow2 grids, N%8==0).
template <int GX, int GY, int GZ>
__device__ __forceinline__ void xcd_swz(int& bx, int& by, int& bz) {
  constexpr int N = GX * GY * GZ;
  int flat = (int)blockIdx.x + GX * ((int)blockIdx.y + GY * (int)blockIdx.z);
  int s = (flat & 7) * (N >> 3) + (flat >> 3);
  bx = s & (GX - 1);
  by = (s / GX) & (GY - 1);
  bz = s / (GX * GY);
}

// T4 pipeline sync: wait with N loads still in flight, then raw barrier.
__device__ __forceinline__ void wait_bar_keep12() {
  asm volatile("s_waitcnt vmcnt(12)" ::: "memory");
  __builtin_amdgcn_s_barrier();
  __builtin_amdgcn_sched_barrier(0);
}
__device__ __forceinline__ void wait_bar_keep8() {
  asm volatile("s_waitcnt vmcnt(8)" ::: "memory");
  __builtin_amdgcn_s_barrier();
  __builtin_amdgcn_sched_barrier(0);
}
__device__ __forceinline__ void wait_bar_keep6() {
  asm volatile("s_waitcnt vmcnt(6)" ::: "memory");
  __builtin_amdgcn_s_barrier();
  __builtin_amdgcn_sched_barrier(0);
}
__device__ __forceinline__ void wait_bar_drain() {
  asm volatile("s_waitcnt vmcnt(0)" ::: "memory");
  __builtin_amdgcn_s_barrier();
  __builtin_amdgcn_sched_barrier(0);
}
__device__ __forceinline__ void end_bar() {
  __builtin_amdgcn_sched_barrier(0);
  __builtin_amdgcn_s_barrier();
}

// Fragment-linear stager (R8): LDS dest lane-linear, GLOBAL source permuted so
// each 16-row subtile lands as [chunk-group h][chunk lk][row lr]; MFMA fragment
// read is subtile_base + h*1024 + lane*16 -> conflict-free.
template <int ROUNDS, int C>
__device__ __forceinline__ void stageF(const char* g, long row0, long ldb,
                                       long k0b, char* l, int tid) {
#pragma unroll
  for (int r = 0; r < ROUNDS; ++r) {
    int s = r * 256 + tid;
    int sub = s / (16 * C);
    int t = s % (16 * C);
    int h = t >> 6;
    int lk = (t >> 4) & 3;
    int lr = t & 15;
    gl_lds16(g + (row0 + sub * 16 + lr) * ldb + k0b + (h * 4 + lk) * 16,
             l + s * 16);
  }
}

// R17/R18: shared f16 GEMM core, 256x128 tile, 4 waves (2M x 2N), wave-tile
// 128x64 (acc 8x4), BK=32, 3-buffer depth-2 counted-vmcnt pipeline.
// LDS layout per buffer (24KB): A 256x32 f16 (16KB) | B 128x32 f16 (8KB).
template <int NT>
__device__ __forceinline__ void gemm256_core(
    const char* A, const char* B, long m0, long n0, long lda, long ldb,
    char* lds, int tid, int wm, int wn, int lane, f32x4 (&acc)[8][4]) {
  auto stage = [&](char* L, int t) {  // 6 gl_lds per thread
    stageF<4, 4>(A, m0, lda, (long)t * 64, L, tid);          // 256x32
    stageF<2, 4>(B, n0, ldb, (long)t * 64, L + 16384, tid);  // 128x32
  };
  auto compute = [&](const char* L) {
    f16x8 af[8], bfr[4];
#pragma unroll
    for (int i = 0; i < 8; ++i)
      af[i] = frag_ld_h(L + (wm * 8 + i) * 1024 + lane * 16);
#pragma unroll
    for (int i = 0; i < 4; ++i)
      bfr[i] = frag_ld_h(L + 16384 + (wn * 4 + i) * 1024 + lane * 16);
    __builtin_amdgcn_s_setprio(1);
#pragma unroll
    for (int mt = 0; mt < 8; ++mt)
#pragma unroll
      for (int nt = 0; nt < 4; ++nt)
        acc[mt][nt] = mfma_f16(af[mt], bfr[nt], acc[mt][nt]);
    __builtin_amdgcn_s_setprio(0);
  };

  char* L0 = lds;
  char* L1 = lds + 24576;
  char* L2 = lds + 49152;
  stage(L0, 0);
  stage(L1, 1);
  for (int t = 0; t < NT - 2; ++t) {
    stage(L2, t + 2);
    wait_bar_keep12();  // 18 outstanding -> 12 == stage(t) landed
    compute(L0);
    end_bar();
    char* tmp = L0; L0 = L1; L1 = L2; L2 = tmp;
  }
  wait_bar_keep6();     // stage(NT-2) landed
  compute(L0);
  end_bar();
  wait_bar_drain();     // stage(NT-1) landed
  compute(L1);
}

// ---------------------------------------------------------------- convert W (fused)
// R21: digitize + transpose Wq/Wk in one pass (z=0,1); Wv -> f16 (z=2).
// Row-major W digits are never materialized (their only reader was the
// transpose).
__global__ void __launch_bounds__(256) convert_wt(
    const float* __restrict__ Wq, const float* __restrict__ Wk,
    const float* __restrict__ Wv,
    u8* __restrict__ wqT0, u8* __restrict__ wqT1,
    u8* __restrict__ wkT0, u8* __restrict__ wkT1, u16* __restrict__ wvh) {
  int a = blockIdx.z;
  int bi = blockIdx.y, bj = blockIdx.x;
  int t = threadIdx.x, r = t >> 2, c4 = t & 3;
  if (a == 2) {
    const float* src = Wv + (long)(bi * 64 + r) * 1024 + bj * 64 + c4 * 16;
    u16* dst = wvh + (long)(bi * 64 + r) * 1024 + bj * 64 + c4 * 16;
#pragma unroll
    for (int j = 0; j < 4; ++j) {
      f32x4 v = ((const f32x4*)src)[j];
      u16x4 h;
#pragma unroll
      for (int e = 0; e < 4; ++e) h[e] = f2h(v[e]);
      ((u16x4*)dst)[j] = h;
    }
    return;
  }
  __shared__ u8 T0[64][68];
  __shared__ u8 T1[64][68];
  const float* src =
      (a ? Wk : Wq) + (long)(bi * 64 + r) * 1024 + bj * 64 + c4 * 16;
#pragma unroll
  for (int j = 0; j < 4; ++j) {
    f32x4 v = ((const f32x4*)src)[j];
#pragma unroll
    for (int e = 0; e < 4; ++e) {
      int d0, d1;
      dig2(v[e], WC, WCI, WFI, d0, d1);
      T0[r][c4 * 16 + j * 4 + e] = (u8)d0;
      T1[r][c4 * 16 + j * 4 + e] = (u8)d1;
    }
  }
  __syncthreads();
  u8* o0 = (a ? wkT0 : wqT0) + (long)(bj * 64 + r) * 1024 + bi * 64 + c4 * 16;
  u8* o1 = (a ? wkT1 : wqT1) + (long)(bj * 64 + r) * 1024 + bi * 64 + c4 * 16;
  u32 p0[4] = {0, 0, 0, 0}, p1[4] = {0, 0, 0, 0};
#pragma unroll
  for (int j = 0; j < 16; ++j) {
    p0[j >> 2] |= ((u32)T0[c4 * 16 + j][r]) << (8 * (j & 3));
    p1[j >> 2] |= ((u32)T1[c4 * 16 + j][r]) << (8 * (j & 3));
  }
#pragma unroll
  for (int j = 0; j < 4; ++j) {
    ((u32*)o0)[j] = p0[j];
    ((u32*)o1)[j] = p1[j];
  }
}

// ---------------------------------------------------------------- gvec
__global__ void __launch_bounds__(256) gvec_kernel(
    const u8* __restrict__ wqT0, const u8* __restrict__ wqT1,
    const u8* __restrict__ wkT0, const u8* __restrict__ wkT1,
    const float* __restrict__ bq, const float* __restrict__ bk,
    float* __restrict__ gq, float* __restrict__ gk, float* __restrict__ cbuf) {
  __shared__ float sbq[1024], sbk[1024];
  int tid = threadIdx.x;
  ((f32x4*)sbq)[tid] = ((const f32x4*)bq)[tid];
  ((f32x4*)sbk)[tid] = ((const f32x4*)bk)[tid];
  __syncthreads();
  int wave = tid >> 6, lane = tid & 63;
#pragma unroll
  for (int rr = 0; rr < 2; ++rr) {
    int d = blockIdx.x * 8 + wave * 2 + rr;
    i8x16 a0 = *(const i8x16*)(wqT0 + (long)d * 1024 + lane * 16);
    i8x16 a1 = *(const i8x16*)(wqT1 + (long)d * 1024 + lane * 16);
    i8x16 c0 = *(const i8x16*)(wkT0 + (long)d * 1024 + lane * 16);
    i8x16 c1 = *(const i8x16*)(wkT1 + (long)d * 1024 + lane * 16);
    float sq = 0.f, sk = 0.f;
#pragma unroll
    for (int j = 0; j < 16; ++j) {
      sq += ((float)a0[j] * WC + (float)a1[j] * W1S) * sbk[lane * 16 + j];
      sk += ((float)c0[j] * WC + (float)c1[j] * W1S) * sbq[lane * 16 + j];
    }
#pragma unroll
    for (int off = 32; off >= 1; off >>= 1) {
      sq += __shfl_xor(sq, off);
      sk += __shfl_xor(sk, off);
    }
    if (!lane) { gq[d] = sq; gk[d] = sk; }
  }
  if (blockIdx.x == 0 && wave == 0) {
    float c = 0.f;
#pragma unroll
    for (int j = 0; j < 16; ++j) c += sbq[lane * 16 + j] * sbk[lane * 16 + j];
#pragma unroll
    for (int off = 32; off >= 1; off >>= 1) c += __shfl_xor(c, off);
    if (!lane) cbuf[0] = c;
  }
}

// ---------------------------------------------------------------- convert x
// f16 (for t/v/score GEMMs) + row dots u, w.
__global__ void __launch_bounds__(256) convert_x(
    const float* __restrict__ x, const float* __restrict__ gq,
    const float* __restrict__ gk, const float* __restrict__ cbuf,
    u16* __restrict__ xh, float* __restrict__ ubuf, float* __restrict__ wbuf) {
  long b = blockIdx.x;
  int tid = threadIdx.x;
  long i = b * 256 + tid;
  f32x4 v = ((const f32x4*)x)[i];
  u16x4 h;
#pragma unroll
  for (int j = 0; j < 4; ++j) h[j] = f2h(v[j]);
  ((u16x4*)xh)[i] = h;

  f32x4 g4 = ((const f32x4*)gq)[tid];
  f32x4 k4 = ((const f32x4*)gk)[tid];
  float pu = v[0] * g4[0] + v[1] * g4[1] + v[2] * g4[2] + v[3] * g4[3];
  float pw = v[0] * k4[0] + v[1] * k4[1] + v[2] * k4[2] + v[3] * k4[3];
#pragma unroll
  for (int off = 32; off >= 1; off >>= 1) {
    pu += __shfl_xor(pu, off);
    pw += __shfl_xor(pw, off);
  }
  __shared__ float ru[4], rw[4];
  int wave = tid >> 6, lane = tid & 63;
  if (!lane) { ru[wave] = pu; rw[wave] = pw; }
  __syncthreads();
  if (!tid) {
    ubuf[b] = ru[0] + ru[1] + ru[2] + ru[3] + cbuf[0];
    wbuf[b] = rw[0] + rw[1] + rw[2] + rw[3];
  }
}

// ---------------------------------------------------------------- G partial GEMM
__global__ void __launch_bounds__(256, 2) g_part(
    const u8* __restrict__ wqT0, const u8* __restrict__ wqT1,
    const u8* __restrict__ wkT0, const u8* __restrict__ wkT1,
    float* __restrict__ Gpart) {
  __shared__ char lds[65536];
  const int tid = threadIdx.x;
  const int bx = blockIdx.x, by = blockIdx.y, bz = blockIdx.z;
  const long m0 = (long)by * 128;
  const int n0 = bx * 128;
  const int k00 = bz * 256;
  const int wave = tid >> 6, lane = tid & 63;
  const int wm = wave >> 1, wn = wave & 1;
  const int lr = lane & 15, lk = lane >> 4;

  i32x4 accM[4][4] = {};
  i32x4 accX[4][4] = {};
  i32x4 accY[4][4] = {};

  auto stage = [&](char* L, int kk) {
    stageF<2, 4>((const char*)wqT0, m0, 1024, kk, L + 0, tid);
    stageF<2, 4>((const char*)wqT1, m0, 1024, kk, L + 8192, tid);
    stageF<2, 4>((const char*)wkT0, n0, 1024, kk, L + 16384, tid);
    stageF<2, 4>((const char*)wkT1, n0, 1024, kk, L + 24576, tid);
  };
  auto compute = [&](const char* L) {
    i32x4 b0[4], b1[4];
#pragma unroll
    for (int nt = 0; nt < 4; ++nt) {
      int rb = (wn * 4 + nt) * 1024 + lane * 16;
      b0[nt] = *(const i32x4*)(L + 16384 + rb);
      b1[nt] = *(const i32x4*)(L + 24576 + rb);
    }
    __builtin_amdgcn_s_setprio(1);
#pragma unroll
    for (int mt = 0; mt < 4; ++mt) {
      int ra = (wm * 4 + mt) * 1024 + lane * 16;
      i32x4 a0 = *(const i32x4*)(L + ra);
      i32x4 a1 = *(const i32x4*)(L + 8192 + ra);
#pragma unroll
      for (int nt = 0; nt < 4; ++nt) {
        accM[mt][nt] = mfma_i8(a0, b0[nt], accM[mt][nt]);
        accX[mt][nt] = mfma_i8(a0, b1[nt], accX[mt][nt]);
        accX[mt][nt] = mfma_i8(a1, b0[nt], accX[mt][nt]);
        accY[mt][nt] = mfma_i8(a1, b1[nt], accY[mt][nt]);
      }
    }
    __builtin_amdgcn_s_setprio(0);
  };

  stage(lds, k00);
  for (int t = 0; t < 3; ++t) {
    char* L = lds + (t & 1) * 32768;
    stage(lds + ((t + 1) & 1) * 32768, k00 + (t + 1) * 64);
    wait_bar_keep8();
    compute(L);
    end_bar();
  }
  {
    char* L = lds + 32768;
    wait_bar_drain();
    compute(L);
  }

#pragma unroll
  for (int mt = 0; mt < 4; ++mt)
#pragma unroll
    for (int nt = 0; nt < 4; ++nt) {
      int e = n0 + wn * 64 + nt * 16 + lr;
      int gmb = (int)m0 + wm * 64 + mt * 16 + lk * 4;
      f32x4 o;
#pragma unroll
      for (int r = 0; r < 4; ++r)
        o[r] = (float)accM[mt][nt][r] * SG00 + (float)accX[mt][nt][r] * SG01 +
               (float)accY[mt][nt][r] * SG11;
      *(f32x4*)(Gpart + ((long)bz << 20) + (long)e * 1024 + gmb) = o;
    }
}

// ---------------------------------------------------------------- G reduce -> f16
__global__ void __launch_bounds__(256) g_reduce(const float* __restrict__ Gpart,
                                                u16* __restrict__ Gh) {
  int n = blockIdx.x, tid = threadIdx.x;
  long o = (long)n * 1024 + tid * 4;
  f32x4 v = *(const f32x4*)(Gpart + o);
  f32x4 v1 = *(const f32x4*)(Gpart + (1L << 20) + o);
  f32x4 v2 = *(const f32x4*)(Gpart + (2L << 20) + o);
  f32x4 v3 = *(const f32x4*)(Gpart + (3L << 20) + o);
  u16x4 h;
#pragma unroll
  for (int j = 0; j < 4; ++j) h[j] = f2h(v[j] + v1[j] + v2[j] + v3[j]);
  ((u16x4*)Gh)[n * 256 + tid] = h;
}

// ---------------------------------------------------------------- t+v GEMM (f16)
// R21: merged. bz=0: t = x G -> th. bz=1: v = x Wv^T + bv -> vt (transposed).
// Core and epilogues are byte-identical to the validated R18 kernels.
__global__ void __launch_bounds__(256, 2) tv_gemm(
    const u16* __restrict__ xh, const u16* __restrict__ Gh,
    const u16* __restrict__ wvh, const float* __restrict__ bv,
    u16* __restrict__ th, u16* __restrict__ vt) {
  __shared__ char lds[73728];
  const int tid = threadIdx.x;
  int bx, by, bz;
  xcd_swz<8, 32, 2>(bx, by, bz);
  const long m0 = (long)by * 256;
  const int n0 = bx * 128;
  const int wave = tid >> 6, lane = tid & 63;
  const int wm = wave >> 1, wn = wave & 1;
  const int lr = lane & 15, lk = lane >> 4;

  const char* B = (const char*)(bz ? wvh : Gh);

  f32x4 acc[8][4] = {};
  gemm256_core<32>((const char*)xh, B, m0, n0,
                   (long)Dd * 2, (long)Dd * 2, lds, tid, wm, wn, lane, acc);

  if (bz == 0) {
#pragma unroll
    for (int mt = 0; mt < 8; ++mt)
#pragma unroll
      for (int nt = 0; nt < 4; ++nt)
#pragma unroll
        for (int r = 0; r < 4; ++r) {
          long gm = m0 + wm * 128 + mt * 16 + lk * 4 + r;
          int e = n0 + wn * 64 + nt * 16 + lr;
          th[gm * Dd + e] = f2h(acc[mt][nt][r]);
        }
  } else {
#pragma unroll
    for (int mt = 0; mt < 8; ++mt)
#pragma unroll
      for (int nt = 0; nt < 4; ++nt)
#pragma unroll
        for (int r = 0; r < 4; ++r) {
          long gm = m0 + wm * 128 + mt * 16 + lk * 4 + r;
          int e = n0 + wn * 64 + nt * 16 + lr;
          float v = acc[mt][nt][r] + bv[e];
          long b = gm >> 11, s = gm & 2047;
          vt[(b * Dd + e) * (long)Ss + s] = f2h(v);
        }
  }
}

// ---------------------------------------------------------------- scores GEMM (f16)
// 256x128 tile, wave-tile 128x64, 3-buffer depth-2 (R17, validated).
__global__ void __launch_bounds__(256, 2) score_gemm(
    const u16* __restrict__ th, const u16* __restrict__ xh,
    const float* __restrict__ ubuf, const float* __restrict__ wbuf,
    float* __restrict__ scores) {
  __shared__ char lds[73728];
  const int tid = threadIdx.x;
  int bx, by, bz;
  xcd_swz<16, 8, 4>(bx, by, bz);
  const int z = bz;  // batch
  const long base = (long)z * Ss * Dd * 2;  // byte offset
  const long m0 = (long)by * 256;
  const int n0 = bx * 128;
  const int wave = tid >> 6, lane = tid & 63;
  const int wm = wave >> 1, wn = wave & 1;
  const int lr = lane & 15, lk = lane >> 4;

  f32x4 acc[8][4] = {};
  gemm256_core<32>((const char*)th + base, (const char*)xh + base, m0, n0,
                   (long)Dd * 2, (long)Dd * 2, lds, tid, wm, wn, lane, acc);

  float* srow = scores + (long)z * Ss * Ss;
#pragma unroll
  for (int mt = 0; mt < 8; ++mt)
#pragma unroll
    for (int nt = 0; nt < 4; ++nt)
#pragma unroll
      for (int r = 0; r < 4; ++r) {
        long i = m0 + wm * 128 + mt * 16 + lk * 4 + r;
        int j = n0 + wn * 64 + nt * 16 + lr;
        srow[i * Ss + j] = acc[mt][nt][r] +
                           ubuf[(z << 11) + i] + wbuf[(z << 11) + j];
      }
}

// ---------------------------------------------------------------- softmax
__global__ void __launch_bounds__(256) softmax_rows(const float* __restrict__ scores,
                                                    u16* __restrict__ P) {
  const long r = blockIdx.x;
  const float* row = scores + r * Ss;
  u16* prow = P + r * Ss;
  const int t = threadIdx.x;
  const int wave = t >> 6, lane = t & 63;
  f32x4 v0 = ((const f32x4*)row)[t * 2];
  f32x4 v1 = ((const f32x4*)row)[t * 2 + 1];
  float a[8];
#pragma unroll
  for (int j = 0; j < 4; ++j) { a[j] = v0[j]; a[4 + j] = v1[j]; }

  float m = a[0];
#pragma unroll
  for (int j = 1; j < 8; ++j) m = fmaxf(m, a[j]);
#pragma unroll
  for (int off = 32; off >= 1; off >>= 1) m = fmaxf(m, __shfl_xor(m, off));
  __shared__ float red[4];
  if (lane == 0) red[wave] = m;
  __syncthreads();
  m = fmaxf(fmaxf(red[0], red[1]), fmaxf(red[2], red[3]));

  float e[8];
  float s = 0.f;
#pragma unroll
  for (int j = 0; j < 8; ++j) { e[j] = __expf(a[j] - m); s += e[j]; }
#pragma unroll
  for (int off = 32; off >= 1; off >>= 1) s += __shfl_xor(s, off);
  __syncthreads();
  if (lane == 0) red[wave] = s;
  __syncthreads();
  s = red[0] + red[1] + red[2] + red[3];
  float inv = 1.0f / s;

  u16x8 pk;
#pragma unroll
  for (int j = 0; j < 8; ++j) pk[j] = f2h(e[j] * inv);
  ((u16x8*)prow)[t] = pk;
}

// ---------------------------------------------------------------- PV GEMM
// 256x128 tile, wave-tile 128x64, NT=64 (R18, validated).
__global__ void __launch_bounds__(256, 2) pv_gemm(const u16* __restrict__ P,
                                                  const u16* __restrict__ vt,
                                                  float* __restrict__ out) {
  __shared__ char lds[73728];
  const int tid = threadIdx.x;
  int bx, by, bz;
  xcd_swz<8, 8, 4>(bx, by, bz);
  const int z = bz;  // batch
  const char* A = (const char*)(P + (long)z * Ss * Ss);
  const char* Bp = (const char*)(vt + (long)z * Dd * Ss);
  const long m0 = (long)by * 256;
  const int n0 = bx * 128;

  const int wave = tid >> 6, lane = tid & 63;
  const int wm = wave >> 1, wn = wave & 1;
  const int lr = lane & 15, lk = lane >> 4;

  f32x4 acc[8][4] = {};
  gemm256_core<64>(A, Bp, m0, n0, (long)Ss * 2, (long)Ss * 2,
                   lds, tid, wm, wn, lane, acc);

  float* orow = out + (long)z * Ss * Dd;
#pragma unroll
  for (int mt = 0; mt < 8; ++mt)
#pragma unroll
    for (int nt = 0; nt < 4; ++nt)
#pragma unroll
      for (int r = 0; r < 4; ++r) {
        long i = m0 + wm * 128 + mt * 16 + lk * 4 + r;
        int e = n0 + wn * 64 + nt * 16 + lr;
        orow[i * Dd + e] = acc[mt][nt][r];
      }
}

// ---------------------------------------------------------------- launch
extern "C" void kernel_launch(void* const* d_in, const int* in_sizes, int n_in,
                              void* d_out, int out_size, void* d_ws, size_t ws_size,
                              hipStream_t stream) {
  const float* x = (const float*)d_in[0];
  const float* Wq = (const float*)d_in[1];
  const float* bq = (const float*)d_in[2];
  const float* Wk = (const float*)d_in[3];
  const float* bk = (const float*)d_in[4];
  const float* Wv = (const float*)d_in[5];
  const float* bv = (const float*)d_in[6];
  float* out = (float*)d_out;

  // workspace carve (~148 MiB). Aliases (writer strictly after aliased reader):
  //   [0,64Mi)   scores          | Gh [0,2Mi) early | wvh [16,18Mi) early
  //   [80,96Mi)  Gpart -> th (th written after g_reduce consumes Gpart)
  //   [96,128Mi) Pbuf            | xh [96,112Mi): dead before softmax writes P
  //   [128,144Mi) vt
  //   [144,148Mi) wqT0..wkT1
  //   [148Mi..)  gq, gk, ubuf, wbuf, cbuf
  char* p = (char*)d_ws;
  float* scores = (float*)p;
  u16* Gh = (u16*)p;                         // 2MB f16 G^T
  u16* wvh = (u16*)(p + (16L << 20));
  u16* th = (u16*)(p + (80L << 20));         // 16MB f16
  float* Gpart = (float*)(p + (80L << 20));  // alias: dead after g_reduce
  u16* Pbuf = (u16*)(p + (96L << 20));
  u16* xh = (u16*)(p + (96L << 20));         // alias: dead before softmax
  u16* vt = (u16*)(p + (128L << 20));
  u8* wqT0 = (u8*)(p + (144L << 20));
  u8* wqT1 = wqT0 + (1L << 20);
  u8* wkT0 = wqT0 + (2L << 20);
  u8* wkT1 = wqT0 + (3L << 20);
  float* gq = (float*)(p + (148L << 20));
  float* gk = gq + 1024;
  float* ubuf = gq + 2048;
  float* wbuf = ubuf + 8192;
  float* cbuf = wbuf + 8192;

  // 1. W: digitize+transpose (q,k) and f16 convert (v), fused
  convert_wt<<<dim3(16, 16, 3), dim3(256), 0, stream>>>(
      Wq, Wk, Wv, wqT0, wqT1, wkT0, wkT1, wvh);
  // 2. gq = Wq^T bk, gk = Wk^T bq, c = bq.bk
  gvec_kernel<<<dim3(128), dim3(256), 0, stream>>>(
      wqT0, wqT1, wkT0, wkT1, bq, bk, gq, gk, cbuf);
  // 3. x f16 + u,w row dots
  convert_x<<<dim3(8192), dim3(256), 0, stream>>>(
      x, gq, gk, cbuf, xh, ubuf, wbuf);
  // 4. G partials (K-split 4, exact i8)
  g_part<<<dim3(8, 8, 4), dim3(256), 0, stream>>>(wqT0, wqT1, wkT0, wkT1, Gpart);
  // 5. reduce -> f16 Gh
  g_reduce<<<dim3(1024), dim3(256), 0, stream>>>(Gpart, Gh);
  // 6. t = x G and v = x Wv^T + bv, merged (th over Gpart which is dead)
  tv_gemm<<<dim3(8, 32, 2), dim3(256), 0, stream>>>(xh, Gh, wvh, bv, th, vt);
  // 7. scores = th x^T + u + w (f16 GEMM, 256x128 tile)
  score_gemm<<<dim3(Ss / 128, Ss / 256, Bb), dim3(256), 0, stream>>>(
      th, xh, ubuf, wbuf, scores);
  // 8. softmax rows -> dense P (overwrites xh, dead)
  softmax_rows<<<dim3(Bb * Ss), dim3(256), 0, stream>>>(scores, Pbuf);
  // 9. out = P @ v (256x128 tile)
  pv_gemm<<<dim3(Dd / 128, Ss / 256, Bb), dim3(256), 0, stream>>>(Pbuf, vt, out);
}

// Round 16
// 299.223 us; speedup vs baseline: 1.0785x; 1.0014x over previous
//
#include <hip/hip_runtime.h>

// SelfAttention: B=4, S=2048, D=1024, fp32 in/out.
// q=x@Wq^T+bq, k=..., v=...; out = softmax(q k^T) @ v   (no 1/sqrt(d) scale)
//
// R11: scores = x G x^T + u 1^T + 1 w^T (G = Wq^T Wk precomputed; one
//   projection GEMM t = x G instead of two; biases exact f32 epilogue adds).
// Carried: R8 fragment-linear LDS (bank conflicts 0), R9 counted-vmcnt +
//   raw s_barrier (T4), R10 XCD swizzle, R13/R15 f16 GEMMs (absmax 0.1016
//   accepted), R17/R18 256x128 tile / wave-tile 128x64 with 3-buffer BK=32
//   depth-2 pipeline at 2 blocks/CU (validated), R21 fused converts + merged
//   tv_gemm (best = 299.6us; all GEMMs traffic-optimal per FETCH counters).
// R22: wave-per-row softmax — one row per WAVE (4 rows/block, 2048 blocks),
//   pure shfl_xor reduction, no LDS, no barriers; fully coalesced f32x4
//   reads / u16x4 writes. GEMMs untouched: they sit at the 2-phase schedule
//   ceiling whose remaining lever (8-phase interleave) needs race screening
//   this loop can't provide.

#define Bb 4
#define Ss 2048
#define Dd 1024
#define Mtot 8192  // B*S

typedef _Float16 f16x8 __attribute__((ext_vector_type(8)));
typedef float f32x4 __attribute__((ext_vector_type(4)));
typedef int i32x4 __attribute__((ext_vector_type(4)));
typedef signed char i8x16 __attribute__((ext_vector_type(16)));
typedef unsigned short u16;
typedef unsigned int u32;
typedef unsigned char u8;
typedef u16 u16x8 __attribute__((ext_vector_type(8)));
typedef u16 u16x4 __attribute__((ext_vector_type(4)));
typedef void __attribute__((address_space(1))) gvoid_t;
typedef void __attribute__((address_space(3))) svoid_t;

// ---- W digit scales (powers of two) ----
#define WC 1.953125e-3f               // 2^-9
#define WCI 512.f
#define WFI 131072.f
#define W1S 7.62939453125e-6f         // 2^-17
// G = Wq^T Wk accumulator scales
#define SG00 3.814697265625e-6f       // 2^-18
#define SG01 1.4901161193847656e-8f   // 2^-26
#define SG11 5.820766091346741e-11f   // 2^-34

__device__ __forceinline__ void gl_lds16(const void* g, void* l) {
  __builtin_amdgcn_global_load_lds((gvoid_t*)g, (svoid_t*)l, 16, 0, 0);
}

__device__ __forceinline__ u16 f2h(float f) {
  return __builtin_bit_cast(u16, (_Float16)f);
}
__device__ __forceinline__ f16x8 frag_ld_h(const char* p) {
  u16x8 v = *(const u16x8*)p;
  return __builtin_bit_cast(f16x8, v);
}
__device__ __forceinline__ f32x4 mfma_f16(f16x8 a, f16x8 b, f32x4 c) {
  return __builtin_amdgcn_mfma_f32_16x16x32_f16(a, b, c, 0, 0, 0);
}
__device__ __forceinline__ i32x4 mfma_i8(i32x4 a, i32x4 b, i32x4 c) {
  return __builtin_amdgcn_mfma_i32_16x16x64_i8(a, b, c, 0, 0, 0);
}
// split v into two clamped i8 digits: v ~= d0*cs + d1*(1/fi)
__device__ __forceinline__ void dig2(float v, float cs, float ci, float fi,
                                     int& d0, int& d1) {
  float t = fminf(fmaxf(v * ci, -127.f), 127.f);
  d0 = __float2int_rn(t);
  float res = v - (float)d0 * cs;
  float u = fminf(fmaxf(res * fi, -127.f), 127.f);
  d1 = __float2int_rn(u);
}

// T1: bijective XCD-aware block swizzle (pow2 grids, N%8==0).
template <int GX, int GY, int GZ>
__device__ __forceinline__ void xcd_swz(int& bx, int& by, int& bz) {
  constexpr int N = GX * GY * GZ;
  int flat = (int)blockIdx.x + GX * ((int)blockIdx.y + GY * (int)blockIdx.z);
  int s = (flat & 7) * (N >> 3) + (flat >> 3);
  bx = s & (GX - 1);
  by = (s / GX) & (GY - 1);
  bz = s / (GX * GY);
}

// T4 pipeline sync: wait with N loads still in flight, then raw barrier.
__device__ __forceinline__ void wait_bar_keep12() {
  asm volatile("s_waitcnt vmcnt(12)" ::: "memory");
  __builtin_amdgcn_s_barrier();
  __builtin_amdgcn_sched_barrier(0);
}
__device__ __forceinline__ void wait_bar_keep8() {
  asm volatile("s_waitcnt vmcnt(8)" ::: "memory");
  __builtin_amdgcn_s_barrier();
  __builtin_amdgcn_sched_barrier(0);
}
__device__ __forceinline__ void wait_bar_keep6() {
  asm volatile("s_waitcnt vmcnt(6)" ::: "memory");
  __builtin_amdgcn_s_barrier();
  __builtin_amdgcn_sched_barrier(0);
}
__device__ __forceinline__ void wait_bar_drain() {
  asm volatile("s_waitcnt vmcnt(0)" ::: "memory");
  __builtin_amdgcn_s_barrier();
  __builtin_amdgcn_sched_barrier(0);
}
__device__ __forceinline__ void end_bar() {
  __builtin_amdgcn_sched_barrier(0);
  __builtin_amdgcn_s_barrier();
}

// Fragment-linear stager (R8): LDS dest lane-linear, GLOBAL source permuted so
// each 16-row subtile lands as [chunk-group h][chunk lk][row lr]; MFMA fragment
// read is subtile_base + h*1024 + lane*16 -> conflict-free.
template <int ROUNDS, int C>
__device__ __forceinline__ void stageF(const char* g, long row0, long ldb,
                                       long k0b, char* l, int tid) {
#pragma unroll
  for (int r = 0; r < ROUNDS; ++r) {
    int s = r * 256 + tid;
    int sub = s / (16 * C);
    int t = s % (16 * C);
    int h = t >> 6;
    int lk = (t >> 4) & 3;
    int lr = t & 15;
    gl_lds16(g + (row0 + sub * 16 + lr) * ldb + k0b + (h * 4 + lk) * 16,
             l + s * 16);
  }
}

// R17/R18: shared f16 GEMM core, 256x128 tile, 4 waves (2M x 2N), wave-tile
// 128x64 (acc 8x4), BK=32, 3-buffer depth-2 counted-vmcnt pipeline.
// LDS layout per buffer (24KB): A 256x32 f16 (16KB) | B 128x32 f16 (8KB).
template <int NT>
__device__ __forceinline__ void gemm256_core(
    const char* A, const char* B, long m0, long n0, long lda, long ldb,
    char* lds, int tid, int wm, int wn, int lane, f32x4 (&acc)[8][4]) {
  auto stage = [&](char* L, int t) {  // 6 gl_lds per thread
    stageF<4, 4>(A, m0, lda, (long)t * 64, L, tid);          // 256x32
    stageF<2, 4>(B, n0, ldb, (long)t * 64, L + 16384, tid);  // 128x32
  };
  auto compute = [&](const char* L) {
    f16x8 af[8], bfr[4];
#pragma unroll
    for (int i = 0; i < 8; ++i)
      af[i] = frag_ld_h(L + (wm * 8 + i) * 1024 + lane * 16);
#pragma unroll
    for (int i = 0; i < 4; ++i)
      bfr[i] = frag_ld_h(L + 16384 + (wn * 4 + i) * 1024 + lane * 16);
    __builtin_amdgcn_s_setprio(1);
#pragma unroll
    for (int mt = 0; mt < 8; ++mt)
#pragma unroll
      for (int nt = 0; nt < 4; ++nt)
        acc[mt][nt] = mfma_f16(af[mt], bfr[nt], acc[mt][nt]);
    __builtin_amdgcn_s_setprio(0);
  };

  char* L0 = lds;
  char* L1 = lds + 24576;
  char* L2 = lds + 49152;
  stage(L0, 0);
  stage(L1, 1);
  for (int t = 0; t < NT - 2; ++t) {
    stage(L2, t + 2);
    wait_bar_keep12();  // 18 outstanding -> 12 == stage(t) landed
    compute(L0);
    end_bar();
    char* tmp = L0; L0 = L1; L1 = L2; L2 = tmp;
  }
  wait_bar_keep6();     // stage(NT-2) landed
  compute(L0);
  end_bar();
  wait_bar_drain();     // stage(NT-1) landed
  compute(L1);
}

// ---------------------------------------------------------------- convert W (fused)
// R21: digitize + transpose Wq/Wk in one pass (z=0,1); Wv -> f16 (z=2).
__global__ void __launch_bounds__(256) convert_wt(
    const float* __restrict__ Wq, const float* __restrict__ Wk,
    const float* __restrict__ Wv,
    u8* __restrict__ wqT0, u8* __restrict__ wqT1,
    u8* __restrict__ wkT0, u8* __restrict__ wkT1, u16* __restrict__ wvh) {
  int a = blockIdx.z;
  int bi = blockIdx.y, bj = blockIdx.x;
  int t = threadIdx.x, r = t >> 2, c4 = t & 3;
  if (a == 2) {
    const float* src = Wv + (long)(bi * 64 + r) * 1024 + bj * 64 + c4 * 16;
    u16* dst = wvh + (long)(bi * 64 + r) * 1024 + bj * 64 + c4 * 16;
#pragma unroll
    for (int j = 0; j < 4; ++j) {
      f32x4 v = ((const f32x4*)src)[j];
      u16x4 h;
#pragma unroll
      for (int e = 0; e < 4; ++e) h[e] = f2h(v[e]);
      ((u16x4*)dst)[j] = h;
    }
    return;
  }
  __shared__ u8 T0[64][68];
  __shared__ u8 T1[64][68];
  const float* src =
      (a ? Wk : Wq) + (long)(bi * 64 + r) * 1024 + bj * 64 + c4 * 16;
#pragma unroll
  for (int j = 0; j < 4; ++j) {
    f32x4 v = ((const f32x4*)src)[j];
#pragma unroll
    for (int e = 0; e < 4; ++e) {
      int d0, d1;
      dig2(v[e], WC, WCI, WFI, d0, d1);
      T0[r][c4 * 16 + j * 4 + e] = (u8)d0;
      T1[r][c4 * 16 + j * 4 + e] = (u8)d1;
    }
  }
  __syncthreads();
  u8* o0 = (a ? wkT0 : wqT0) + (long)(bj * 64 + r) * 1024 + bi * 64 + c4 * 16;
  u8* o1 = (a ? wkT1 : wqT1) + (long)(bj * 64 + r) * 1024 + bi * 64 + c4 * 16;
  u32 p0[4] = {0, 0, 0, 0}, p1[4] = {0, 0, 0, 0};
#pragma unroll
  for (int j = 0; j < 16; ++j) {
    p0[j >> 2] |= ((u32)T0[c4 * 16 + j][r]) << (8 * (j & 3));
    p1[j >> 2] |= ((u32)T1[c4 * 16 + j][r]) << (8 * (j & 3));
  }
#pragma unroll
  for (int j = 0; j < 4; ++j) {
    ((u32*)o0)[j] = p0[j];
    ((u32*)o1)[j] = p1[j];
  }
}

// ---------------------------------------------------------------- gvec
__global__ void __launch_bounds__(256) gvec_kernel(
    const u8* __restrict__ wqT0, const u8* __restrict__ wqT1,
    const u8* __restrict__ wkT0, const u8* __restrict__ wkT1,
    const float* __restrict__ bq, const float* __restrict__ bk,
    float* __restrict__ gq, float* __restrict__ gk, float* __restrict__ cbuf) {
  __shared__ float sbq[1024], sbk[1024];
  int tid = threadIdx.x;
  ((f32x4*)sbq)[tid] = ((const f32x4*)bq)[tid];
  ((f32x4*)sbk)[tid] = ((const f32x4*)bk)[tid];
  __syncthreads();
  int wave = tid >> 6, lane = tid & 63;
#pragma unroll
  for (int rr = 0; rr < 2; ++rr) {
    int d = blockIdx.x * 8 + wave * 2 + rr;
    i8x16 a0 = *(const i8x16*)(wqT0 + (long)d * 1024 + lane * 16);
    i8x16 a1 = *(const i8x16*)(wqT1 + (long)d * 1024 + lane * 16);
    i8x16 c0 = *(const i8x16*)(wkT0 + (long)d * 1024 + lane * 16);
    i8x16 c1 = *(const i8x16*)(wkT1 + (long)d * 1024 + lane * 16);
    float sq = 0.f, sk = 0.f;
#pragma unroll
    for (int j = 0; j < 16; ++j) {
      sq += ((float)a0[j] * WC + (float)a1[j] * W1S) * sbk[lane * 16 + j];
      sk += ((float)c0[j] * WC + (float)c1[j] * W1S) * sbq[lane * 16 + j];
    }
#pragma unroll
    for (int off = 32; off >= 1; off >>= 1) {
      sq += __shfl_xor(sq, off);
      sk += __shfl_xor(sk, off);
    }
    if (!lane) { gq[d] = sq; gk[d] = sk; }
  }
  if (blockIdx.x == 0 && wave == 0) {
    float c = 0.f;
#pragma unroll
    for (int j = 0; j < 16; ++j) c += sbq[lane * 16 + j] * sbk[lane * 16 + j];
#pragma unroll
    for (int off = 32; off >= 1; off >>= 1) c += __shfl_xor(c, off);
    if (!lane) cbuf[0] = c;
  }
}

// ---------------------------------------------------------------- convert x
// f16 (for t/v/score GEMMs) + row dots u, w.
__global__ void __launch_bounds__(256) convert_x(
    const float* __restrict__ x, const float* __restrict__ gq,
    const float* __restrict__ gk, const float* __restrict__ cbuf,
    u16* __restrict__ xh, float* __restrict__ ubuf, float* __restrict__ wbuf) {
  long b = blockIdx.x;
  int tid = threadIdx.x;
  long i = b * 256 + tid;
  f32x4 v = ((const f32x4*)x)[i];
  u16x4 h;
#pragma unroll
  for (int j = 0; j < 4; ++j) h[j] = f2h(v[j]);
  ((u16x4*)xh)[i] = h;

  f32x4 g4 = ((const f32x4*)gq)[tid];
  f32x4 k4 = ((const f32x4*)gk)[tid];
  float pu = v[0] * g4[0] + v[1] * g4[1] + v[2] * g4[2] + v[3] * g4[3];
  float pw = v[0] * k4[0] + v[1] * k4[1] + v[2] * k4[2] + v[3] * k4[3];
#pragma unroll
  for (int off = 32; off >= 1; off >>= 1) {
    pu += __shfl_xor(pu, off);
    pw += __shfl_xor(pw, off);
  }
  __shared__ float ru[4], rw[4];
  int wave = tid >> 6, lane = tid & 63;
  if (!lane) { ru[wave] = pu; rw[wave] = pw; }
  __syncthreads();
  if (!tid) {
    ubuf[b] = ru[0] + ru[1] + ru[2] + ru[3] + cbuf[0];
    wbuf[b] = rw[0] + rw[1] + rw[2] + rw[3];
  }
}

// ---------------------------------------------------------------- G partial GEMM
__global__ void __launch_bounds__(256, 2) g_part(
    const u8* __restrict__ wqT0, const u8* __restrict__ wqT1,
    const u8* __restrict__ wkT0, const u8* __restrict__ wkT1,
    float* __restrict__ Gpart) {
  __shared__ char lds[65536];
  const int tid = threadIdx.x;
  const int bx = blockIdx.x, by = blockIdx.y, bz = blockIdx.z;
  const long m0 = (long)by * 128;
  const int n0 = bx * 128;
  const int k00 = bz * 256;
  const int wave = tid >> 6, lane = tid & 63;
  const int wm = wave >> 1, wn = wave & 1;
  const int lr = lane & 15, lk = lane >> 4;

  i32x4 accM[4][4] = {};
  i32x4 accX[4][4] = {};
  i32x4 accY[4][4] = {};

  auto stage = [&](char* L, int kk) {
    stageF<2, 4>((const char*)wqT0, m0, 1024, kk, L + 0, tid);
    stageF<2, 4>((const char*)wqT1, m0, 1024, kk, L + 8192, tid);
    stageF<2, 4>((const char*)wkT0, n0, 1024, kk, L + 16384, tid);
    stageF<2, 4>((const char*)wkT1, n0, 1024, kk, L + 24576, tid);
  };
  auto compute = [&](const char* L) {
    i32x4 b0[4], b1[4];
#pragma unroll
    for (int nt = 0; nt < 4; ++nt) {
      int rb = (wn * 4 + nt) * 1024 + lane * 16;
      b0[nt] = *(const i32x4*)(L + 16384 + rb);
      b1[nt] = *(const i32x4*)(L + 24576 + rb);
    }
    __builtin_amdgcn_s_setprio(1);
#pragma unroll
    for (int mt = 0; mt < 4; ++mt) {
      int ra = (wm * 4 + mt) * 1024 + lane * 16;
      i32x4 a0 = *(const i32x4*)(L + ra);
      i32x4 a1 = *(const i32x4*)(L + 8192 + ra);
#pragma unroll
      for (int nt = 0; nt < 4; ++nt) {
        accM[mt][nt] = mfma_i8(a0, b0[nt], accM[mt][nt]);
        accX[mt][nt] = mfma_i8(a0, b1[nt], accX[mt][nt]);
        accX[mt][nt] = mfma_i8(a1, b0[nt], accX[mt][nt]);
        accY[mt][nt] = mfma_i8(a1, b1[nt], accY[mt][nt]);
      }
    }
    __builtin_amdgcn_s_setprio(0);
  };

  stage(lds, k00);
  for (int t = 0; t < 3; ++t) {
    char* L = lds + (t & 1) * 32768;
    stage(lds + ((t + 1) & 1) * 32768, k00 + (t + 1) * 64);
    wait_bar_keep8();
    compute(L);
    end_bar();
  }
  {
    char* L = lds + 32768;
    wait_bar_drain();
    compute(L);
  }

#pragma unroll
  for (int mt = 0; mt < 4; ++mt)
#pragma unroll
    for (int nt = 0; nt < 4; ++nt) {
      int e = n0 + wn * 64 + nt * 16 + lr;
      int gmb = (int)m0 + wm * 64 + mt * 16 + lk * 4;
      f32x4 o;
#pragma unroll
      for (int r = 0; r < 4; ++r)
        o[r] = (float)accM[mt][nt][r] * SG00 + (float)accX[mt][nt][r] * SG01 +
               (float)accY[mt][nt][r] * SG11;
      *(f32x4*)(Gpart + ((long)bz << 20) + (long)e * 1024 + gmb) = o;
    }
}

// ---------------------------------------------------------------- G reduce -> f16
__global__ void __launch_bounds__(256) g_reduce(const float* __restrict__ Gpart,
                                                u16* __restrict__ Gh) {
  int n = blockIdx.x, tid = threadIdx.x;
  long o = (long)n * 1024 + tid * 4;
  f32x4 v = *(const f32x4*)(Gpart + o);
  f32x4 v1 = *(const f32x4*)(Gpart + (1L << 20) + o);
  f32x4 v2 = *(const f32x4*)(Gpart + (2L << 20) + o);
  f32x4 v3 = *(const f32x4*)(Gpart + (3L << 20) + o);
  u16x4 h;
#pragma unroll
  for (int j = 0; j < 4; ++j) h[j] = f2h(v[j] + v1[j] + v2[j] + v3[j]);
  ((u16x4*)Gh)[n * 256 + tid] = h;
}

// ---------------------------------------------------------------- t+v GEMM (f16)
// R21: merged. bz=0: t = x G -> th. bz=1: v = x Wv^T + bv -> vt (transposed).
__global__ void __launch_bounds__(256, 2) tv_gemm(
    const u16* __restrict__ xh, const u16* __restrict__ Gh,
    const u16* __restrict__ wvh, const float* __restrict__ bv,
    u16* __restrict__ th, u16* __restrict__ vt) {
  __shared__ char lds[73728];
  const int tid = threadIdx.x;
  int bx, by, bz;
  xcd_swz<8, 32, 2>(bx, by, bz);
  const long m0 = (long)by * 256;
  const int n0 = bx * 128;
  const int wave = tid >> 6, lane = tid & 63;
  const int wm = wave >> 1, wn = wave & 1;
  const int lr = lane & 15, lk = lane >> 4;

  const char* B = (const char*)(bz ? wvh : Gh);

  f32x4 acc[8][4] = {};
  gemm256_core<32>((const char*)xh, B, m0, n0,
                   (long)Dd * 2, (long)Dd * 2, lds, tid, wm, wn, lane, acc);

  if (bz == 0) {
#pragma unroll
    for (int mt = 0; mt < 8; ++mt)
#pragma unroll
      for (int nt = 0; nt < 4; ++nt)
#pragma unroll
        for (int r = 0; r < 4; ++r) {
          long gm = m0 + wm * 128 + mt * 16 + lk * 4 + r;
          int e = n0 + wn * 64 + nt * 16 + lr;
          th[gm * Dd + e] = f2h(acc[mt][nt][r]);
        }
  } else {
#pragma unroll
    for (int mt = 0; mt < 8; ++mt)
#pragma unroll
      for (int nt = 0; nt < 4; ++nt)
#pragma unroll
        for (int r = 0; r < 4; ++r) {
          long gm = m0 + wm * 128 + mt * 16 + lk * 4 + r;
          int e = n0 + wn * 64 + nt * 16 + lr;
          float v = acc[mt][nt][r] + bv[e];
          long b = gm >> 11, s = gm & 2047;
          vt[(b * Dd + e) * (long)Ss + s] = f2h(v);
        }
  }
}

// ---------------------------------------------------------------- scores GEMM (f16)
// 256x128 tile, wave-tile 128x64, 3-buffer depth-2 (R17, validated).
__global__ void __launch_bounds__(256, 2) score_gemm(
    const u16* __restrict__ th, const u16* __restrict__ xh,
    const float* __restrict__ ubuf, const float* __restrict__ wbuf,
    float* __restrict__ scores) {
  __shared__ char lds[73728];
  const int tid = threadIdx.x;
  int bx, by, bz;
  xcd_swz<16, 8, 4>(bx, by, bz);
  const int z = bz;  // batch
  const long base = (long)z * Ss * Dd * 2;  // byte offset
  const long m0 = (long)by * 256;
  const int n0 = bx * 128;
  const int wave = tid >> 6, lane = tid & 63;
  const int wm = wave >> 1, wn = wave & 1;
  const int lr = lane & 15, lk = lane >> 4;

  f32x4 acc[8][4] = {};
  gemm256_core<32>((const char*)th + base, (const char*)xh + base, m0, n0,
                   (long)Dd * 2, (long)Dd * 2, lds, tid, wm, wn, lane, acc);

  float* srow = scores + (long)z * Ss * Ss;
#pragma unroll
  for (int mt = 0; mt < 8; ++mt)
#pragma unroll
    for (int nt = 0; nt < 4; ++nt)
#pragma unroll
      for (int r = 0; r < 4; ++r) {
        long i = m0 + wm * 128 + mt * 16 + lk * 4 + r;
        int j = n0 + wn * 64 + nt * 16 + lr;
        srow[i * Ss + j] = acc[mt][nt][r] +
                           ubuf[(z << 11) + i] + wbuf[(z << 11) + j];
      }
}

// ---------------------------------------------------------------- softmax
// R22: one row per WAVE (4 rows/block), no LDS, no barriers; coalesced
// f32x4 reads / u16x4 writes; 64-lane shfl_xor reductions.
__global__ void __launch_bounds__(256) softmax_rows(const float* __restrict__ scores,
                                                    u16* __restrict__ P) {
  const int wave = threadIdx.x >> 6, lane = threadIdx.x & 63;
  const long r = (long)blockIdx.x * 4 + wave;
  const float* row = scores + r * Ss;
  u16* prow = P + r * Ss;

  f32x4 v[8];
#pragma unroll
  for (int i = 0; i < 8; ++i) v[i] = ((const f32x4*)row)[i * 64 + lane];

  float m = v[0][0];
#pragma unroll
  for (int i = 0; i < 8; ++i)
#pragma unroll
    for (int j = 0; j < 4; ++j) m = fmaxf(m, v[i][j]);
#pragma unroll
  for (int off = 32; off >= 1; off >>= 1) m = fmaxf(m, __shfl_xor(m, off));

  float s = 0.f;
#pragma unroll
  for (int i = 0; i < 8; ++i)
#pragma unroll
    for (int j = 0; j < 4; ++j) {
      v[i][j] = __expf(v[i][j] - m);
      s += v[i][j];
    }
#pragma unroll
  for (int off = 32; off >= 1; off >>= 1) s += __shfl_xor(s, off);
  float inv = 1.0f / s;

#pragma unroll
  for (int i = 0; i < 8; ++i) {
    u16x4 pk;
#pragma unroll
    for (int j = 0; j < 4; ++j) pk[j] = f2h(v[i][j] * inv);
    ((u16x4*)prow)[i * 64 + lane] = pk;
  }
}

// ---------------------------------------------------------------- PV GEMM
// 256x128 tile, wave-tile 128x64, NT=64 (R18, validated).
__global__ void __launch_bounds__(256, 2) pv_gemm(const u16* __restrict__ P,
                                                  const u16* __restrict__ vt,
                                                  float* __restrict__ out) {
  __shared__ char lds[73728];
  const int tid = threadIdx.x;
  int bx, by, bz;
  xcd_swz<8, 8, 4>(bx, by, bz);
  const int z = bz;  // batch
  const char* A = (const char*)(P + (long)z * Ss * Ss);
  const char* Bp = (const char*)(vt + (long)z * Dd * Ss);
  const long m0 = (long)by * 256;
  const int n0 = bx * 128;

  const int wave = tid >> 6, lane = tid & 63;
  const int wm = wave >> 1, wn = wave & 1;
  const int lr = lane & 15, lk = lane >> 4;

  f32x4 acc[8][4] = {};
  gemm256_core<64>(A, Bp, m0, n0, (long)Ss * 2, (long)Ss * 2,
                   lds, tid, wm, wn, lane, acc);

  float* orow = out + (long)z * Ss * Dd;
#pragma unroll
  for (int mt = 0; mt < 8; ++mt)
#pragma unroll
    for (int nt = 0; nt < 4; ++nt)
#pragma unroll
      for (int r = 0; r < 4; ++r) {
        long i = m0 + wm * 128 + mt * 16 + lk * 4 + r;
        int e = n0 + wn * 64 + nt * 16 + lr;
        orow[i * Dd + e] = acc[mt][nt][r];
      }
}

// ---------------------------------------------------------------- launch
extern "C" void kernel_launch(void* const* d_in, const int* in_sizes, int n_in,
                              void* d_out, int out_size, void* d_ws, size_t ws_size,
                              hipStream_t stream) {
  const float* x = (const float*)d_in[0];
  const float* Wq = (const float*)d_in[1];
  const float* bq = (const float*)d_in[2];
  const float* Wk = (const float*)d_in[3];
  const float* bk = (const float*)d_in[4];
  const float* Wv = (const float*)d_in[5];
  const float* bv = (const float*)d_in[6];
  float* out = (float*)d_out;

  // workspace carve (~148 MiB). Aliases (writer strictly after aliased reader):
  //   [0,64Mi)   scores          | Gh [0,2Mi) early | wvh [16,18Mi) early
  //   [80,96Mi)  Gpart -> th (th written after g_reduce consumes Gpart)
  //   [96,128Mi) Pbuf            | xh [96,112Mi): dead before softmax writes P
  //   [128,144Mi) vt
  //   [144,148Mi) wqT0..wkT1
  //   [148Mi..)  gq, gk, ubuf, wbuf, cbuf
  char* p = (char*)d_ws;
  float* scores = (float*)p;
  u16* Gh = (u16*)p;                         // 2MB f16 G^T
  u16* wvh = (u16*)(p + (16L << 20));
  u16* th = (u16*)(p + (80L << 20));         // 16MB f16
  float* Gpart = (float*)(p + (80L << 20));  // alias: dead after g_reduce
  u16* Pbuf = (u16*)(p + (96L << 20));
  u16* xh = (u16*)(p + (96L << 20));         // alias: dead before softmax
  u16* vt = (u16*)(p + (128L << 20));
  u8* wqT0 = (u8*)(p + (144L << 20));
  u8* wqT1 = wqT0 + (1L << 20);
  u8* wkT0 = wqT0 + (2L << 20);
  u8* wkT1 = wqT0 + (3L << 20);
  float* gq = (float*)(p + (148L << 20));
  float* gk = gq + 1024;
  float* ubuf = gq + 2048;
  float* wbuf = ubuf + 8192;
  float* cbuf = wbuf + 8192;

  // 1. W: digitize+transpose (q,k) and f16 convert (v), fused
  convert_wt<<<dim3(16, 16, 3), dim3(256), 0, stream>>>(
      Wq, Wk, Wv, wqT0, wqT1, wkT0, wkT1, wvh);
  // 2. gq = Wq^T bk, gk = Wk^T bq, c = bq.bk
  gvec_kernel<<<dim3(128), dim3(256), 0, stream>>>(
      wqT0, wqT1, wkT0, wkT1, bq, bk, gq, gk, cbuf);
  // 3. x f16 + u,w row dots
  convert_x<<<dim3(8192), dim3(256), 0, stream>>>(
      x, gq, gk, cbuf, xh, ubuf, wbuf);
  // 4. G partials (K-split 4, exact i8)
  g_part<<<dim3(8, 8, 4), dim3(256), 0, stream>>>(wqT0, wqT1, wkT0, wkT1, Gpart);
  // 5. reduce -> f16 Gh
  g_reduce<<<dim3(1024), dim3(256), 0, stream>>>(Gpart, Gh);
  // 6. t = x G and v = x Wv^T + bv, merged (th over Gpart which is dead)
  tv_gemm<<<dim3(8, 32, 2), dim3(256), 0, stream>>>(xh, Gh, wvh, bv, th, vt);
  // 7. scores = th x^T + u + w (f16 GEMM, 256x128 tile)
  score_gemm<<<dim3(Ss / 128, Ss / 256, Bb), dim3(256), 0, stream>>>(
      th, xh, ubuf, wbuf, scores);
  // 8. softmax rows -> dense P (wave-per-row; overwrites xh, dead)
  softmax_rows<<<dim3(Bb * Ss / 4), dim3(256), 0, stream>>>(scores, Pbuf);
  // 9. out = P @ v (256x128 tile)
  pv_gemm<<<dim3(Dd / 128, Ss / 256, Bb), dim3(256), 0, stream>>>(Pbuf, vt, out);
}